// Round 2
// baseline (996.898 us; speedup 1.0000x reference)
//
#include <hip/hip_runtime.h>
#include <hip/hip_fp16.h>

// SpectralAttention: B=4, S=1024, E=1024, H=16, HD=64.
// Identity: real(ifft2(F*exp(i*phi))) == ifft2(F * cos(phi)) for real scores
// => real spectral gain, Hermitian half-spectrum (v=0..512).
//
// Round-7: k4 processes TWO v-rows per wave (shared twiddles, 2x ILP per
// stage) and uses the exact identity cos(atan t) = rsqrt(1+t^2) when
// alpha == 1 (wave-uniform), removing precise atanf/cosf from the hot path.
// k23/k56/k1/k7 unchanged from round-6.
//
// Workspace (~64.1 MiB): Q 8M | Kb 8M | Vt 8M | ctx 8M | Ct 32.06M | flags

typedef __attribute__((ext_vector_type(8))) short short8;
typedef __attribute__((ext_vector_type(4))) float f32x4;

#define PITCH 40
#define PADI(i) ((i) + ((i) >> 4))   // 1024 logical -> 1088 physical float2
#define XROW 1088

__device__ __forceinline__ float bf2f(short v) {
  return __uint_as_float(((unsigned)(unsigned short)v) << 16);
}
__device__ __forceinline__ short f2bf(float f) {
  unsigned u = __float_as_uint(f);
  u += 0x7FFFu + ((u >> 16) & 1u);  // RNE
  return (short)(u >> 16);
}

__device__ __forceinline__ short8 ld8(const void* p, size_t idx, int isf32) {
  short8 r;
  if (isf32) {
    const float* f = (const float*)p + idx;
    float4 a = *(const float4*)f;
    float4 b = *(const float4*)(f + 4);
    r[0] = f2bf(a.x); r[1] = f2bf(a.y); r[2] = f2bf(a.z); r[3] = f2bf(a.w);
    r[4] = f2bf(b.x); r[5] = f2bf(b.y); r[6] = f2bf(b.z); r[7] = f2bf(b.w);
  } else {
    r = *(const short8*)((const short*)p + idx);
  }
  return r;
}
__device__ __forceinline__ float ldf(const void* p, int idx, int isf32) {
  return isf32 ? ((const float*)p)[idx] : bf2f(((const short*)p)[idx]);
}

__device__ __forceinline__ float2 cmul(float2 a, float2 b) {
  return make_float2(a.x * b.x - a.y * b.y, a.x * b.y + a.y * b.x);
}
__device__ __forceinline__ float2 cmulc(float2 a, float2 b) {  // a * conj(b)
  return make_float2(a.x * b.x + a.y * b.y, a.y * b.x - a.x * b.y);
}
__device__ __forceinline__ float2 cadd(float2 a, float2 b) {
  return make_float2(a.x + b.x, a.y + b.y);
}
__device__ __forceinline__ float2 csub(float2 a, float2 b) {
  return make_float2(a.x - b.x, a.y - b.y);
}
// base-4 digit reversal of 10-bit index (involution)
__device__ __forceinline__ int dr4(int p) {
  return ((p & 3) << 8) | (((p >> 2) & 3) << 6) | (((p >> 4) & 3) << 4) |
         (((p >> 6) & 3) << 2) | ((p >> 8) & 3);
}

// ================== wave-register 1024-pt FFT (16 in-reg x 64 cross-lane) ==
// Layout: lane l holds z[l + 64*j], j=0..15 (n1 = lane, n2 = reg).
// Forward DIF output: (lane l, reg r) holds F[bitrev4(r) + 16*bitrev6(l)].
// wfft1024_dif<-1> = true DFT (W^-), <+1> = unnormalized inverse (W^+).
// wfft1024_inv = exact stage-mirror of wfft1024_dif<-1>; dif(-1) o inv = 1024*I.

template <int SGN>
__device__ __forceinline__ void dft16_dif(float2* x) {
  const float C16[8] = {1.f, 0.92387953f, 0.70710678f, 0.38268343f,
                        0.f, -0.38268343f, -0.70710678f, -0.92387953f};
  const float S16[8] = {0.f, 0.38268343f, 0.70710678f, 0.92387953f,
                        1.f, 0.92387953f, 0.70710678f, 0.38268343f};
#pragma unroll
  for (int h = 8; h >= 1; h >>= 1)
#pragma unroll
    for (int b = 0; b < 16; b += 2 * h)
#pragma unroll
      for (int i = 0; i < h; ++i) {
        const int e = i * (8 / h);
        float2 u = x[b + i], v = x[b + i + h];
        x[b + i] = cadd(u, v);
        float2 d = csub(u, v);
        float2 w = make_float2(C16[e], SGN > 0 ? S16[e] : -S16[e]);
        x[b + i + h] = (e == 0) ? d : cmul(d, w);
      }
}

__device__ __forceinline__ void dit16_inv(float2* x) {
  const float C16[8] = {1.f, 0.92387953f, 0.70710678f, 0.38268343f,
                        0.f, -0.38268343f, -0.70710678f, -0.92387953f};
  const float S16[8] = {0.f, 0.38268343f, 0.70710678f, 0.92387953f,
                        1.f, 0.92387953f, 0.70710678f, 0.38268343f};
#pragma unroll
  for (int h = 1; h <= 8; h <<= 1)
#pragma unroll
    for (int b = 0; b < 16; b += 2 * h)
#pragma unroll
      for (int i = 0; i < h; ++i) {
        const int e = i * (8 / h);
        float2 w = make_float2(C16[e], -S16[e]);
        float2 u = x[b + i];
        float2 vh = (e == 0) ? x[b + i + h] : cmulc(x[b + i + h], w);
        x[b + i] = cadd(u, vh);
        x[b + i + h] = csub(u, vh);
      }
}

template <int SGN>
__device__ __forceinline__ void midtw(float2* x, int lane) {
  // reg r holds k2 = bitrev4(r); apply W_1024^{SGN * lane * k2}.
  const int rho[16] = {0, 8, 4, 12, 2, 10, 6, 14, 1, 9, 5, 13, 3, 11, 7, 15};
  float s, c;
  __sincosf((float)lane * 0.00613592315f, &s, &c);  // 2pi/1024
  float2 w = make_float2(c, SGN > 0 ? s : -s);
  float2 run = w;
  x[8] = cmul(x[8], run);  // power e=1 -> reg rho[1]=8
#pragma unroll
  for (int e = 2; e < 16; ++e) {
    run = cmul(run, w);
    x[rho[e]] = cmul(x[rho[e]], run);
  }
}

__device__ __forceinline__ void midtw_inv(float2* x, int lane) {
  const int rho[16] = {0, 8, 4, 12, 2, 10, 6, 14, 1, 9, 5, 13, 3, 11, 7, 15};
  float s, c;
  __sincosf((float)lane * 0.00613592315f, &s, &c);
  float2 w = make_float2(c, -s);  // forward twiddle; conj applied via cmulc
  float2 run = w;
  x[8] = cmulc(x[8], run);
#pragma unroll
  for (int e = 2; e < 16; ++e) {
    run = cmul(run, w);
    x[rho[e]] = cmulc(x[rho[e]], run);
  }
}

template <int SGN>
__device__ __forceinline__ void xlane_dif(float2* x, int lane) {
#pragma unroll
  for (int h = 32; h >= 1; h >>= 1) {
    const int e = (lane & (h - 1)) * (32 / h);  // W_64 exponent
    float s, c;
    __sincosf((float)e * 0.09817477042f, &s, &c);  // 2pi/64
    float2 w = make_float2(c, SGN > 0 ? s : -s);
    const bool hi = (lane & h) != 0;
#pragma unroll
    for (int r = 0; r < 16; ++r) {
      float2 t = x[r];
      float2 p;
      p.x = __shfl_xor(t.x, h, 64);
      p.y = __shfl_xor(t.y, h, 64);
      x[r] = hi ? cmul(csub(p, t), w) : cadd(t, p);  // hi: (u - v)*w
    }
  }
}

__device__ __forceinline__ void xlane_dit_inv(float2* x, int lane) {
#pragma unroll
  for (int h = 1; h <= 32; h <<= 1) {
    const int e = (lane & (h - 1)) * (32 / h);
    float s, c;
    __sincosf((float)e * 0.09817477042f, &s, &c);
    float2 w = make_float2(c, -s);  // forward twiddle; conj via cmulc
    const bool hi = (lane & h) != 0;
#pragma unroll
    for (int r = 0; r < 16; ++r) {
      float2 t = x[r];
      if (hi) t = cmulc(t, w);  // v_hat = v * conj(w) BEFORE exchange
      float2 p;
      p.x = __shfl_xor(t.x, h, 64);
      p.y = __shfl_xor(t.y, h, 64);
      x[r] = hi ? csub(p, t) : cadd(t, p);  // hi: u - v_hat ; lo: u + v_hat
    }
  }
}

template <int SGN>
__device__ __forceinline__ void wfft1024_dif(float2* x, int lane) {
  dft16_dif<SGN>(x);
  midtw<SGN>(x, lane);
  xlane_dif<SGN>(x, lane);
}
__device__ __forceinline__ void wfft1024_inv(float2* x, int lane) {
  xlane_dit_inv(x, lane);
  midtw_inv(x, lane);
  dit16_inv(x);
}

// -------- paired (two-row) variants: shared twiddles, 2x ILP per stage ----
template <int SGN>
__device__ __forceinline__ void midtw2(float2* x, float2* y, int lane) {
  const int rho[16] = {0, 8, 4, 12, 2, 10, 6, 14, 1, 9, 5, 13, 3, 11, 7, 15};
  float s, c;
  __sincosf((float)lane * 0.00613592315f, &s, &c);  // 2pi/1024
  float2 w = make_float2(c, SGN > 0 ? s : -s);
  float2 run = w;
  x[8] = cmul(x[8], run);
  y[8] = cmul(y[8], run);
#pragma unroll
  for (int e = 2; e < 16; ++e) {
    run = cmul(run, w);
    x[rho[e]] = cmul(x[rho[e]], run);
    y[rho[e]] = cmul(y[rho[e]], run);
  }
}

__device__ __forceinline__ void midtw_inv2(float2* x, float2* y, int lane) {
  const int rho[16] = {0, 8, 4, 12, 2, 10, 6, 14, 1, 9, 5, 13, 3, 11, 7, 15};
  float s, c;
  __sincosf((float)lane * 0.00613592315f, &s, &c);
  float2 w = make_float2(c, -s);
  float2 run = w;
  x[8] = cmulc(x[8], run);
  y[8] = cmulc(y[8], run);
#pragma unroll
  for (int e = 2; e < 16; ++e) {
    run = cmul(run, w);
    x[rho[e]] = cmulc(x[rho[e]], run);
    y[rho[e]] = cmulc(y[rho[e]], run);
  }
}

template <int SGN>
__device__ __forceinline__ void xlane_dif2(float2* x, float2* y, int lane) {
#pragma unroll
  for (int h = 32; h >= 1; h >>= 1) {
    const int e = (lane & (h - 1)) * (32 / h);
    float s, c;
    __sincosf((float)e * 0.09817477042f, &s, &c);  // 2pi/64
    float2 w = make_float2(c, SGN > 0 ? s : -s);
    const bool hi = (lane & h) != 0;
#pragma unroll
    for (int r = 0; r < 16; ++r) {
      float2 t = x[r];
      float2 p;
      p.x = __shfl_xor(t.x, h, 64);
      p.y = __shfl_xor(t.y, h, 64);
      x[r] = hi ? cmul(csub(p, t), w) : cadd(t, p);
    }
#pragma unroll
    for (int r = 0; r < 16; ++r) {
      float2 t = y[r];
      float2 p;
      p.x = __shfl_xor(t.x, h, 64);
      p.y = __shfl_xor(t.y, h, 64);
      y[r] = hi ? cmul(csub(p, t), w) : cadd(t, p);
    }
  }
}

__device__ __forceinline__ void xlane_dit_inv2(float2* x, float2* y, int lane) {
#pragma unroll
  for (int h = 1; h <= 32; h <<= 1) {
    const int e = (lane & (h - 1)) * (32 / h);
    float s, c;
    __sincosf((float)e * 0.09817477042f, &s, &c);
    float2 w = make_float2(c, -s);
    const bool hi = (lane & h) != 0;
#pragma unroll
    for (int r = 0; r < 16; ++r) {
      float2 t = x[r];
      if (hi) t = cmulc(t, w);
      float2 p;
      p.x = __shfl_xor(t.x, h, 64);
      p.y = __shfl_xor(t.y, h, 64);
      x[r] = hi ? csub(p, t) : cadd(t, p);
    }
#pragma unroll
    for (int r = 0; r < 16; ++r) {
      float2 t = y[r];
      if (hi) t = cmulc(t, w);
      float2 p;
      p.x = __shfl_xor(t.x, h, 64);
      p.y = __shfl_xor(t.y, h, 64);
      y[r] = hi ? csub(p, t) : cadd(t, p);
    }
  }
}

template <int SGN>
__device__ __forceinline__ void wfft1024_dif2(float2* x, float2* y, int lane) {
  dft16_dif<SGN>(x);
  dft16_dif<SGN>(y);
  midtw2<SGN>(x, y, lane);
  xlane_dif2<SGN>(x, y, lane);
}
__device__ __forceinline__ void wfft1024_inv2(float2* x, float2* y, int lane) {
  xlane_dit_inv2(x, y, lane);
  midtw_inv2(x, y, lane);
  dit16_inv(x);
  dit16_inv(y);
}

// ------------------------------------------------- k0: dtype detect + alpha
__global__ void k0_detect(const unsigned* __restrict__ q,
                          const void* __restrict__ alphap, int* __restrict__ flags) {
  __shared__ float smax[256];
  __shared__ int szero[256];
  int t = threadIdx.x;
  float mx = 0.f; int zc = 0;
  for (int i = t; i < 16384; i += 256) {
    unsigned w = q[i];
    unsigned lo = w & 0xFFFFu;
    float v = fabsf(__uint_as_float(lo << 16));
    if (!(v <= 1e30f)) v = 1e30f;
    mx = fmaxf(mx, v);
    zc += (lo == 0u);
  }
  smax[t] = mx; szero[t] = zc;
  __syncthreads();
  for (int s = 128; s > 0; s >>= 1) {
    if (t < s) { smax[t] = fmaxf(smax[t], smax[t + s]); szero[t] += szero[t + s]; }
    __syncthreads();
  }
  if (t == 0) {
    int isf32 = (smax[0] > 100.f) || (szero[0] > 12288);
    flags[0] = isf32;
    float alpha = isf32 ? *(const float*)alphap : bf2f(*(const short*)alphap);
    ((float*)flags)[1] = alpha;
  }
}

// ------------------------------------------------- k1: QKV projection (XCD-swizzled)
__global__ __launch_bounds__(256) void k1_qkv(
    const void* __restrict__ x,
    const void* __restrict__ Wq, const void* __restrict__ bq,
    const void* __restrict__ Wk, const void* __restrict__ bk,
    const void* __restrict__ Wv, const void* __restrict__ bv,
    short* __restrict__ Qo, short* __restrict__ Ko, short* __restrict__ Vt,
    const int* __restrict__ flags)
{
  __shared__ __align__(16) char smem[128 * 136 * 2];
  short* As = (short*)smem;
  short* Bs = As + 128 * PITCH;
  short* Ct = (short*)smem;
  const int isf32 = flags[0];
  const int t = threadIdx.x;
  const int lb = blockIdx.x;
  const int m0 = ((lb & 7) * 4 + ((lb >> 3) & 3)) * 128;
  const int n0 = (lb >> 5) * 128;
  const int which = blockIdx.y;
  const void* __restrict__ W = (which == 0) ? Wq : (which == 1) ? Wk : Wv;
  const void* __restrict__ bias = (which == 0) ? bq : (which == 1) ? bk : bv;
  const int lane = t & 63, wvi = t >> 6;
  const int wr = wvi >> 1, wc = wvi & 1;
  const int lm = lane & 15, lq = lane >> 4;
  f32x4 acc[4][4] = {};

  for (int k0 = 0; k0 < 1024; k0 += 32) {
    __syncthreads();
#pragma unroll
    for (int i = 0; i < 2; ++i) {
      int l = t + i * 256;
      int row = l >> 2, kk = (l & 3) << 3;
      *(short8*)&As[row * PITCH + kk] = ld8(x, (size_t)(m0 + row) * 1024 + k0 + kk, isf32);
      *(short8*)&Bs[row * PITCH + kk] = ld8(W, (size_t)(n0 + row) * 1024 + k0 + kk, isf32);
    }
    __syncthreads();
    short8 af[4], bf[4];
#pragma unroll
    for (int a = 0; a < 4; ++a) af[a] = *(const short8*)&As[(wr * 64 + a * 16 + lm) * PITCH + lq * 8];
#pragma unroll
    for (int b = 0; b < 4; ++b) bf[b] = *(const short8*)&Bs[(wc * 64 + b * 16 + lm) * PITCH + lq * 8];
#pragma unroll
    for (int a = 0; a < 4; ++a)
#pragma unroll
      for (int b = 0; b < 4; ++b)
        acc[a][b] = __builtin_amdgcn_mfma_f32_16x16x32_bf16(af[a], bf[b], acc[a][b], 0, 0, 0);
  }

  __syncthreads();
#pragma unroll
  for (int a = 0; a < 4; ++a)
#pragma unroll
    for (int b = 0; b < 4; ++b) {
      int col = wc * 64 + b * 16 + lm;
      float bv_ = ldf(bias, n0 + col, isf32);
#pragma unroll
      for (int r = 0; r < 4; ++r) {
        int row = wr * 64 + a * 16 + lq * 4 + r;
        Ct[row * 136 + col] = f2bf(acc[a][b][r] + bv_);
      }
    }
  __syncthreads();

  if (which != 2) {
    short* __restrict__ O = (which == 1) ? Ko : Qo;
#pragma unroll
    for (int j = 0; j < 8; ++j) {
      int id = t + j * 256;
      int row = id >> 4, c16 = (id & 15) * 8;
      short8 v = *(const short8*)&Ct[row * 136 + c16];
      int col = n0 + c16;
      int h = col >> 6, d = col & 63;
      int n = m0 + row, bb = n >> 10, s = n & 1023;
      *(short8*)&O[(((size_t)(bb * 16 + h)) << 16) + ((size_t)s << 6) + d] = v;
    }
  } else {
#pragma unroll
    for (int j = 0; j < 8; ++j) {
      int id = t + j * 256;
      int d128 = id & 127, sg = (id >> 7) * 8;
      short vals[8];
#pragma unroll
      for (int i = 0; i < 8; ++i) vals[i] = Ct[(sg + i) * 136 + d128];
      int col = n0 + d128;
      int h = col >> 6, d = col & 63;
      int bb = m0 >> 10, sbase = (m0 & 1023) + sg;
      *(short8*)&Vt[(((size_t)(bb * 16 + h)) << 16) + ((size_t)d << 10) + sbase] = *(short8*)vals;
    }
  }
}

// ------------------------------------------------- block-FFT helpers (k23 only)
__device__ __forceinline__ void init_tw(float2* tw, int tid) {
  for (int j = tid; j < 512; j += 256) {
    float a = (float)j * (6.283185307179586f / 1024.0f);
    float s, c;
    __sincosf(a, &s, &c);
    tw[j] = make_float2(c, -s);  // W_1024^j
  }
}

// In-place radix-4, padded X (XROW float2), 256 threads, 1 butterfly/thread/stage.
// fwd: natural -> digit-rev.  inv: digit-rev -> natural (unnormalized).
template <bool INV>
__device__ __forceinline__ void fftr4(float2* X, const float2* tw, int tid) {
#pragma unroll
  for (int si = 0; si < 5; ++si) {
    const int st = INV ? 4 - si : si;
    const int L = 1024 >> (2 * st), q = L >> 2, sh = 8 - 2 * st;
    __syncthreads();
    int k = tid & (q - 1), g = tid >> sh;
    int idx = g * L + k;
    int e = k << (2 * st);
    float2 w1 = tw[e], w2 = tw[2 * e];
    int i0 = PADI(idx), i1 = PADI(idx + q), i2 = PADI(idx + 2 * q), i3 = PADI(idx + 3 * q);
    float2 x0 = X[i0], x1 = X[i1], x2 = X[i2], x3 = X[i3];
    if (!INV) {
      float2 w3 = cmul(w1, w2);
      float2 t0 = make_float2(x0.x + x2.x, x0.y + x2.y);
      float2 t1 = make_float2(x0.x - x2.x, x0.y - x2.y);
      float2 t2 = make_float2(x1.x + x3.x, x1.y + x3.y);
      float2 t3 = make_float2(x1.x - x3.x, x1.y - x3.y);
      X[i0] = make_float2(t0.x + t2.x, t0.y + t2.y);
      X[i1] = cmul(make_float2(t1.x + t3.y, t1.y - t3.x), w1);  // t1 - i t3
      X[i2] = cmul(make_float2(t0.x - t2.x, t0.y - t2.y), w2);
      X[i3] = cmul(make_float2(t1.x - t3.y, t1.y + t3.x), w3);  // t1 + i t3
    } else {
      float2 w3 = cmul(w1, w2);
      float2 y1 = cmulc(x1, w1), y2 = cmulc(x2, w2), y3 = cmulc(x3, w3);
      float2 t0 = make_float2(x0.x + y2.x, x0.y + y2.y);
      float2 t1 = make_float2(x0.x - y2.x, x0.y - y2.y);
      float2 t2 = make_float2(y1.x + y3.x, y1.y + y3.y);
      float2 t3 = make_float2(y1.x - y3.x, y1.y - y3.y);
      X[i0] = make_float2(t0.x + t2.x, t0.y + t2.y);
      X[i1] = make_float2(t1.x - t3.y, t1.y + t3.x);  // t1 + i t3
      X[i2] = make_float2(t0.x - t2.x, t0.y - t2.y);
      X[i3] = make_float2(t1.x + t3.y, t1.y - t3.x);  // t1 - i t3
    }
  }
  __syncthreads();
}

// ------------------------------------------------- k23: scores + paired row FFT
__global__ __launch_bounds__(256) void k23_scores_fft(
    const short* __restrict__ Q, const short* __restrict__ Kb,
    __half2* __restrict__ Ct, int bh0)
{
  __shared__ float2 X[XROW];
  __shared__ float2 tw[512];
  __shared__ __half2 Fbuf[16 * 513];
  __shared__ __align__(16) short Qs[16 * 80];
  const int tid = threadIdx.x;
  const int q0 = blockIdx.x * 16;
  const int z = blockIdx.y;
  const int lane = tid & 63, w = tid >> 6;
  const int lm = lane & 15, lq = lane >> 4;
  init_tw(tw, tid);
  const short* __restrict__ Qp = Q + ((size_t)(bh0 + z) << 16);
  const short* __restrict__ Kp = Kb + ((size_t)(bh0 + z) << 16);
  if (tid < 128) {
    int row = tid >> 3, sl = tid & 7;
    *(int4*)&Qs[row * 80 + sl * 8] = *(const int4*)&Qp[(size_t)(q0 + row) * 64 + sl * 8];
  }
  __syncthreads();

  f32x4 acc[16] = {};
  short8 af0 = *(const short8*)&Qs[lm * 80 + lq * 8];
  short8 af1 = *(const short8*)&Qs[lm * 80 + 32 + lq * 8];
#pragma unroll
  for (int t = 0; t < 16; ++t) {
    int n0 = (w * 16 + t) * 16;
    short8 b0 = *(const short8*)&Kp[(size_t)(n0 + lm) * 64 + lq * 8];
    short8 b1 = *(const short8*)&Kp[(size_t)(n0 + lm) * 64 + 32 + lq * 8];
    acc[t] = __builtin_amdgcn_mfma_f32_16x16x32_bf16(af0, b0, acc[t], 0, 0, 0);
    acc[t] = __builtin_amdgcn_mfma_f32_16x16x32_bf16(af1, b1, acc[t], 0, 0, 0);
  }

#pragma unroll 1
  for (int p = 0; p < 8; ++p) {
    __syncthreads();  // X free (prior unpack done)
    if (lq == (p >> 1)) {
#pragma unroll
      for (int t = 0; t < 16; ++t) {
        float lo = (p & 1) ? acc[t][2] : acc[t][0];
        float hi = (p & 1) ? acc[t][3] : acc[t][1];
        X[PADI((w * 16 + t) * 16 + lm)] = make_float2(lo * 0.125f, hi * 0.125f);
      }
    }
    fftr4<false>(X, tw, tid);  // digit-reversed result
    for (int v = tid; v < 513; v += 256) {
      int wn = (1024 - v) & 1023;
      float2 A = X[PADI(dr4(v))], B = X[PADI(dr4(wn))];
      // F1 = (Z + conj(Z~))/2 ; F2 = (Z - conj(Z~))/(2i)
      Fbuf[(2 * p) * 513 + v]     = __float22half2_rn(make_float2((A.x + B.x) * 0.5f, (A.y - B.y) * 0.5f));
      Fbuf[(2 * p + 1) * 513 + v] = __float22half2_rn(make_float2((A.y + B.y) * 0.5f, (B.x - A.x) * 0.5f));
    }
  }
  __syncthreads();
  __half2* out = Ct + (size_t)z * 513 * 1024;
  for (int id = tid; id < 2052; id += 256) {
    int v = id >> 2, qq = (id & 3) * 4;
    int4 o;
    __half2* op = (__half2*)&o;
#pragma unroll
    for (int i = 0; i < 4; ++i) op[i] = Fbuf[(qq + i) * 513 + v];
    *(int4*)&out[(size_t)v * 1024 + q0 + qq] = o;
  }
}

// ------------------------------------------------- k4: column FFT + gain + iFFT
// Wave-register FFT, TWO v-rows per wave: shared twiddles, double ILP.
// alpha==1 fast path: cos(atan t) == rsqrt(1 + t^2) exactly.
__global__ __launch_bounds__(256) void k4_colfft(__half2* __restrict__ Ct,
                                                  const int* __restrict__ flags)
{
  const int lane = threadIdx.x & 63;
  const int w = threadIdx.x >> 6;
  const int gv0 = blockIdx.x * 8 + w * 2;
  if (gv0 > 512) return;
  const int gv1 = gv0 + 1;
  const bool has1 = (gv1 <= 512);
  const float alpha = ((const float*)flags)[1];
  const bool a1 = (alpha == 1.0f);
  __half2* __restrict__ base = Ct + (size_t)blockIdx.y * 513 * 1024;
  __half2* __restrict__ row0 = base + (size_t)gv0 * 1024;
  __half2* __restrict__ row1 = base + (size_t)gv1 * 1024;

  float2 x[16], y[16];
#pragma unroll
  for (int j = 0; j < 16; ++j) x[j] = __half22float2(row0[lane + 64 * j]);
  if (has1) {
#pragma unroll
    for (int j = 0; j < 16; ++j) y[j] = __half22float2(row1[lane + 64 * j]);
  } else {
#pragma unroll
    for (int j = 0; j < 16; ++j) y[j] = make_float2(0.f, 0.f);
  }

  wfft1024_dif2<-1>(x, y, lane);  // true DFT (values exact, order scrambled)

  // real spectral gain (elementwise, order-invariant); 1/N^2 folded in
  if (a1) {
#pragma unroll
    for (int j = 0; j < 16; ++j) {
      {
        float mag2 = x[j].x * x[j].x + x[j].y * x[j].y;
        float t = 0.5f * __logf(mag2 + 1e-20f);
        float wf = __builtin_amdgcn_rsqf(fmaf(t, t, 1.0f)) * (1.0f / 1048576.0f);
        x[j] = make_float2(x[j].x * wf, x[j].y * wf);
      }
      {
        float mag2 = y[j].x * y[j].x + y[j].y * y[j].y;
        float t = 0.5f * __logf(mag2 + 1e-20f);
        float wf = __builtin_amdgcn_rsqf(fmaf(t, t, 1.0f)) * (1.0f / 1048576.0f);
        y[j] = make_float2(y[j].x * wf, y[j].y * wf);
      }
    }
  } else {
#pragma unroll
    for (int j = 0; j < 16; ++j) {
      {
        float mag2 = x[j].x * x[j].x + x[j].y * x[j].y;
        float wf = __cosf(alpha * atanf(0.5f * __logf(mag2 + 1e-20f))) * (1.0f / 1048576.0f);
        x[j] = make_float2(x[j].x * wf, x[j].y * wf);
      }
      {
        float mag2 = y[j].x * y[j].x + y[j].y * y[j].y;
        float wf = __cosf(alpha * atanf(0.5f * __logf(mag2 + 1e-20f))) * (1.0f / 1048576.0f);
        y[j] = make_float2(y[j].x * wf, y[j].y * wf);
      }
    }
  }

  wfft1024_inv2(x, y, lane);  // exact mirror: back to natural order, x1024

#pragma unroll
  for (int j = 0; j < 16; ++j) row0[lane + 64 * j] = __float22half2_rn(x[j]);
  if (has1) {
#pragma unroll
    for (int j = 0; j < 16; ++j) row1[lane + 64 * j] = __float22half2_rn(y[j]);
  }
}

// ------------------------------------------------- k56: inverse row FFT + softmax + PV
// Wave-register inverse FFT (sigma=+1 DIF): wave w owns p-pair {w, w+4}.
// GP overlay: P rows (bf16, pitch 2080B, from 0) grow while Gbuf rows (half2,
// pitch 2052B, from 448) are consumed. Intra-round barrier separates all G
// reads from all P writes (wave 3's P rows would otherwise clobber wave 2's
// unread G row tail).
__global__ __launch_bounds__(256) void k56_softmax_av(
    const __half2* __restrict__ Ct, const short* __restrict__ Vt,
    short* __restrict__ ctx, int bh0)
{
  __shared__ __align__(16) char GP[33280];
  const int tid = threadIdx.x;
  const int q0 = blockIdx.x * 16, z = blockIdx.y;
  const int lane = tid & 63, w = tid >> 6;
  const int lm = lane & 15, lq = lane >> 4;
  const __half2* __restrict__ in = Ct + (size_t)z * 513 * 1024;
#define GROW(m) ((__half2*)(GP + 448 + (m) * 2052))
  for (int id = tid; id < 2052; id += 256) {
    int v = id >> 2, qq = (id & 3) * 4;
    int4 o = *(const int4*)&in[(size_t)v * 1024 + q0 + qq];
    __half2* op = (__half2*)&o;
#pragma unroll
    for (int i = 0; i < 4; ++i) GROW(qq + i)[v] = op[i];
  }
  short* P = (short*)GP;  // row m at m*1040 shorts
  // bitrev6(lane): output k = bitrev4(reg) + 16*bitrev6(lane)
  const int bl6 = ((lane & 1) << 5) | ((lane & 2) << 3) | ((lane & 4) << 1) |
                  ((lane & 8) >> 1) | ((lane & 16) >> 3) | ((lane & 32) >> 5);
  __syncthreads();  // Gbuf ready

#pragma unroll 1
  for (int round = 0; round < 2; ++round) {
    const int p = w + round * 4;
    const __half2* g1 = GROW(2 * p);
    const __half2* g2 = GROW(2 * p + 1);
    float2 x[16];
    // gather z[v] = G1[v] + i*G2[v], Hermitian mirror for v>512 (natural order)
#pragma unroll
    for (int j = 0; j < 16; ++j) {
      int v = lane + 64 * j;
      float2 a, b;
      if (v <= 512) {
        a = __half22float2(g1[v]);
        b = __half22float2(g2[v]);
      } else {
        int v2 = 1024 - v;
        float2 aa = __half22float2(g1[v2]), bb = __half22float2(g2[v2]);
        a = make_float2(aa.x, -aa.y);
        b = make_float2(bb.x, -bb.y);
      }
      x[j] = make_float2(a.x - b.y, a.y + b.x);
    }

    wfft1024_dif<1>(x, lane);  // sum_v z W^{+vk}: Re = row 2p, Im = row 2p+1

    // wave-local softmax (rows are wave-private: 1024 elems over 64 lanes x 16 regs)
    float m1 = -3.4e38f, m2 = -3.4e38f;
#pragma unroll
    for (int j = 0; j < 16; ++j) { m1 = fmaxf(m1, x[j].x); m2 = fmaxf(m2, x[j].y); }
#pragma unroll
    for (int s = 32; s > 0; s >>= 1) {
      m1 = fmaxf(m1, __shfl_xor(m1, s, 64));
      m2 = fmaxf(m2, __shfl_xor(m2, s, 64));
    }
    float s1 = 0.f, s2 = 0.f;
#pragma unroll
    for (int j = 0; j < 16; ++j) {
      float e1 = __expf(x[j].x - m1), e2 = __expf(x[j].y - m2);
      x[j] = make_float2(e1, e2);
      s1 += e1; s2 += e2;
    }
#pragma unroll
    for (int s = 32; s > 0; s >>= 1) {
      s1 += __shfl_xor(s1, s, 64);
      s2 += __shfl_xor(s2, s, 64);
    }
    float inv1 = 1.0f / s1, inv2 = 1.0f / s2;

    __syncthreads();  // ALL G reads of this round done before ANY P writes

    const int rho[16] = {0, 8, 4, 12, 2, 10, 6, 14, 1, 9, 5, 13, 3, 11, 7, 15};
#pragma unroll
    for (int j = 0; j < 16; ++j) {
      int k = rho[j] + 16 * bl6;
      P[(2 * p) * 1040 + k]     = f2bf(x[j].x * inv1);
      P[(2 * p + 1) * 1040 + k] = f2bf(x[j].y * inv2);
    }
  }
  __syncthreads();  // P complete

  // PV: wave w covers k in [w*256, w*256+256)
  const short* __restrict__ Vp = Vt + ((size_t)(bh0 + z) << 16);
  f32x4 acc[4] = {};
#pragma unroll
  for (int ks = 0; ks < 8; ++ks) {
    int k0 = w * 256 + ks * 32;
    short8 a0 = *(const short8*)&P[lm * 1040 + k0 + lq * 8];
#pragma unroll
    for (int b = 0; b < 4; ++b) {
      short8 bv = *(const short8*)&Vp[(size_t)(b * 16 + lm) * 1024 + k0 + lq * 8];
      acc[b] = __builtin_amdgcn_mfma_f32_16x16x32_bf16(a0, bv, acc[b], 0, 0, 0);
    }
  }
  __syncthreads();  // all P reads done; reuse GP for reduction
  float* red = (float*)GP;  // [w][q=16][d=64]
#pragma unroll
  for (int b = 0; b < 4; ++b)
#pragma unroll
    for (int r = 0; r < 4; ++r)
      red[(w * 16 + lq * 4 + r) * 64 + b * 16 + lm] = acc[b][r];
  __syncthreads();
  {
    int q = tid >> 4, d0 = (tid & 15) * 4;
    float s0 = 0.f, s1 = 0.f, s2 = 0.f, s3 = 0.f;
#pragma unroll
    for (int ww = 0; ww < 4; ++ww) {
      const float* rr = &red[(ww * 16 + q) * 64 + d0];
      s0 += rr[0]; s1 += rr[1]; s2 += rr[2]; s3 += rr[3];
    }
    short o4[4] = {f2bf(s0), f2bf(s1), f2bf(s2), f2bf(s3)};
    *(int2*)&ctx[(((size_t)(bh0 + z)) << 16) + (size_t)(q0 + q) * 64 + d0] = *(int2*)o4;
  }
#undef GROW
}

// ------------------------------------------------- k7: out = ctx @ Wo^T + bo (XCD-swizzled)
__global__ __launch_bounds__(256) void k7_out(
    const short* __restrict__ ctx, const void* __restrict__ Wo,
    const void* __restrict__ bo, void* __restrict__ out,
    const int* __restrict__ flags)
{
  __shared__ __align__(16) char smem[128 * 136 * 2];
  short* As = (short*)smem;
  short* Bs = As + 128 * PITCH;
  short* Ct = (short*)smem;
  const int isf32 = flags[0];
  const int t = threadIdx.x;
  const int lb = blockIdx.x;
  const int m0 = ((lb & 7) * 4 + ((lb >> 3) & 3)) * 128;
  const int n0 = (lb >> 5) * 128;
  const int lane = t & 63, wvi = t >> 6;
  const int wr = wvi >> 1, wc = wvi & 1;
  const int lm = lane & 15, lq = lane >> 4;
  f32x4 acc[4][4] = {};

  for (int k0 = 0; k0 < 1024; k0 += 32) {
    __syncthreads();
#pragma unroll
    for (int i = 0; i < 2; ++i) {
      int l = t + i * 256;
      int row = l >> 2, kk = (l & 3) << 3;
      int n = m0 + row, e = k0 + kk;
      size_t aaddr = (((size_t)((n >> 10) * 16 + (e >> 6))) << 16) + (size_t)((n & 1023) << 6) + (e & 63);
      *(int4*)&As[row * PITCH + kk] = *(const int4*)&ctx[aaddr];
      *(short8*)&Bs[row * PITCH + kk] = ld8(Wo, (size_t)(n0 + row) * 1024 + e, isf32);
    }
    __syncthreads();
    short8 af[4], bf[4];
#pragma unroll
    for (int a = 0; a < 4; ++a) af[a] = *(const short8*)&As[(wr * 64 + a * 16 + lm) * PITCH + lq * 8];
#pragma unroll
    for (int b = 0; b < 4; ++b) bf[b] = *(const short8*)&Bs[(wc * 64 + b * 16 + lm) * PITCH + lq * 8];
#pragma unroll
    for (int a = 0; a < 4; ++a)
#pragma unroll
      for (int b = 0; b < 4; ++b)
        acc[a][b] = __builtin_amdgcn_mfma_f32_16x16x32_bf16(af[a], bf[b], acc[a][b], 0, 0, 0);
  }

  if (isf32) {
#pragma unroll
    for (int a = 0; a < 4; ++a)
#pragma unroll
      for (int b = 0; b < 4; ++b) {
        int col = n0 + wc * 64 + b * 16 + lm;
        float bo_ = ldf(bo, col, 1);
#pragma unroll
        for (int r = 0; r < 4; ++r) {
          int row = m0 + wr * 64 + a * 16 + lq * 4 + r;
          ((float*)out)[(size_t)row * 1024 + col] = acc[a][b][r] + bo_;
        }
      }
    return;
  }
  __syncthreads();
#pragma unroll
  for (int a = 0; a < 4; ++a)
#pragma unroll
    for (int b = 0; b < 4; ++b) {
      int col = wc * 64 + b * 16 + lm;
      float bo_ = ldf(bo, n0 + col, 0);
#pragma unroll
      for (int r = 0; r < 4; ++r) {
        int row = wr * 64 + a * 16 + lq * 4 + r;
        Ct[row * 136 + col] = f2bf(acc[a][b][r] + bo_);
      }
    }
  __syncthreads();
#pragma unroll
  for (int j = 0; j < 8; ++j) {
    int id = t + j * 256;
    int row = id >> 4, c16 = (id & 15) * 8;
    short8 v = *(const short8*)&Ct[row * 136 + c16];
    *(short8*)&((short*)out)[(size_t)(m0 + row) * 1024 + n0 + c16] = v;
  }
}

// ------------------------------------------------- launch
extern "C" void kernel_launch(void* const* d_in, const int* in_sizes, int n_in,
                              void* d_out, int out_size, void* d_ws, size_t ws_size,
                              hipStream_t stream)
{
  const void* x  = d_in[0];
  const void* Wq = d_in[1];
  const void* bq = d_in[2];
  const void* Wk = d_in[3];
  const void* bk = d_in[4];
  const void* Wv = d_in[5];
  const void* bv = d_in[6];
  const void* Wo = d_in[7];
  const void* bo = d_in[8];
  const void* alphap = d_in[9];
  char* ws = (char*)d_ws;

  short*   Q    = (short*)(ws);
  short*   Kb   = (short*)(ws + (size_t)( 8u << 20));
  short*   Vt   = (short*)(ws + (size_t)(16u << 20));
  short*   ctx  = (short*)(ws + (size_t)(24u << 20));
  __half2* Ct   = (__half2*)(ws + (size_t)(32u << 20));
  int*     flags = (int*)(ws + (size_t)(32u << 20) + (size_t)16 * 513 * 1024 * 4);

  k0_detect<<<1, 256, 0, stream>>>((const unsigned*)x, alphap, flags);
  k1_qkv<<<dim3(256, 3), 256, 0, stream>>>(x, Wq, bq, Wk, bk, Wv, bv, Q, Kb, Vt, flags);
  for (int c = 0; c < 4; ++c) {
    int bh0 = c * 16;
    k23_scores_fft<<<dim3(64, 16), 256, 0, stream>>>(Q, Kb, Ct, bh0);
    k4_colfft<<<dim3(65, 16), 256, 0, stream>>>(Ct, flags);
    k56_softmax_av<<<dim3(64, 16), 256, 0, stream>>>(Ct, Vt, ctx, bh0);
  }
  k7_out<<<256, 256, 0, stream>>>(ctx, Wo, bo, d_out, flags);
}

// Round 3
// 905.863 us; speedup vs baseline: 1.1005x; 1.1005x over previous
//
#include <hip/hip_runtime.h>
#include <hip/hip_fp16.h>

// SpectralAttention: B=4, S=1024, E=1024, H=16, HD=64.
// Identity: real(ifft2(F*exp(i*phi))) == ifft2(F * cos(phi)) for real scores
// => real spectral gain, Hermitian half-spectrum (v=0..512).
//
// Round-8: ALGEBRAIC RESTRUCTURE. The forward 2D FFT commutes with the
// score GEMM:  F2D[u][v] = sum_d Qhat[u][d] * Khat[v][d], where Qhat/Khat
// are FFTs of the 64 d-columns of Q/K. So:
//   kA: 64 column-FFTs per plane (Q: scrambled-u out, K: natural-v split)
//   kB: complex fp16 MFMA GEMM (513 x 1024 x 64) + fused spectral gain
//   k4_invfft: inverse u-FFT only (k23 and k4's forward half are GONE)
//   k56/k1/k7 unchanged (k1 now emits Q,K,V all transposed [d][s]).
// Qhat slots are stored in the wave-FFT scramble order; kB is slot-wise
// linear; wfft1024_inv consumes exactly that order => no u-scatter at all.
//
// Workspace (~53.5 MiB): Qt 8M | Kt 8M | Vt 8M | ctx 8M | Ct 16.8M (8 planes)
//                        | Qhat 2.1M | Khat 1.06M | flags

typedef __attribute__((ext_vector_type(8))) short short8;
typedef __attribute__((ext_vector_type(8))) _Float16 half8;
typedef __attribute__((ext_vector_type(4))) float f32x4;

#define PITCH 40

__device__ __forceinline__ float bf2f(short v) {
  return __uint_as_float(((unsigned)(unsigned short)v) << 16);
}
__device__ __forceinline__ short f2bf(float f) {
  unsigned u = __float_as_uint(f);
  u += 0x7FFFu + ((u >> 16) & 1u);  // RNE
  return (short)(u >> 16);
}

__device__ __forceinline__ short8 ld8(const void* p, size_t idx, int isf32) {
  short8 r;
  if (isf32) {
    const float* f = (const float*)p + idx;
    float4 a = *(const float4*)f;
    float4 b = *(const float4*)(f + 4);
    r[0] = f2bf(a.x); r[1] = f2bf(a.y); r[2] = f2bf(a.z); r[3] = f2bf(a.w);
    r[4] = f2bf(b.x); r[5] = f2bf(b.y); r[6] = f2bf(b.z); r[7] = f2bf(b.w);
  } else {
    r = *(const short8*)((const short*)p + idx);
  }
  return r;
}
__device__ __forceinline__ float ldf(const void* p, int idx, int isf32) {
  return isf32 ? ((const float*)p)[idx] : bf2f(((const short*)p)[idx]);
}

__device__ __forceinline__ float2 cmul(float2 a, float2 b) {
  return make_float2(a.x * b.x - a.y * b.y, a.x * b.y + a.y * b.x);
}
__device__ __forceinline__ float2 cmulc(float2 a, float2 b) {  // a * conj(b)
  return make_float2(a.x * b.x + a.y * b.y, a.y * b.x - a.x * b.y);
}
__device__ __forceinline__ float2 cadd(float2 a, float2 b) {
  return make_float2(a.x + b.x, a.y + b.y);
}
__device__ __forceinline__ float2 csub(float2 a, float2 b) {
  return make_float2(a.x - b.x, a.y - b.y);
}

// ================== wave-register 1024-pt FFT (16 in-reg x 64 cross-lane) ==
// Layout: lane l holds z[l + 64*j], j=0..15 (n1 = lane, n2 = reg).
// Forward DIF output: (lane l, reg r) holds F[bitrev4(r) + 16*bitrev6(l)].
// wfft1024_dif<-1> = true DFT (W^-), <+1> = unnormalized inverse (W^+).
// wfft1024_inv2 = exact stage-mirror of dif<-1>; dif(-1) o inv = 1024*I.

template <int SGN>
__device__ __forceinline__ void dft16_dif(float2* x) {
  const float C16[8] = {1.f, 0.92387953f, 0.70710678f, 0.38268343f,
                        0.f, -0.38268343f, -0.70710678f, -0.92387953f};
  const float S16[8] = {0.f, 0.38268343f, 0.70710678f, 0.92387953f,
                        1.f, 0.92387953f, 0.70710678f, 0.38268343f};
#pragma unroll
  for (int h = 8; h >= 1; h >>= 1)
#pragma unroll
    for (int b = 0; b < 16; b += 2 * h)
#pragma unroll
      for (int i = 0; i < h; ++i) {
        const int e = i * (8 / h);
        float2 u = x[b + i], v = x[b + i + h];
        x[b + i] = cadd(u, v);
        float2 d = csub(u, v);
        float2 w = make_float2(C16[e], SGN > 0 ? S16[e] : -S16[e]);
        x[b + i + h] = (e == 0) ? d : cmul(d, w);
      }
}

__device__ __forceinline__ void dit16_inv(float2* x) {
  const float C16[8] = {1.f, 0.92387953f, 0.70710678f, 0.38268343f,
                        0.f, -0.38268343f, -0.70710678f, -0.92387953f};
  const float S16[8] = {0.f, 0.38268343f, 0.70710678f, 0.92387953f,
                        1.f, 0.92387953f, 0.70710678f, 0.38268343f};
#pragma unroll
  for (int h = 1; h <= 8; h <<= 1)
#pragma unroll
    for (int b = 0; b < 16; b += 2 * h)
#pragma unroll
      for (int i = 0; i < h; ++i) {
        const int e = i * (8 / h);
        float2 w = make_float2(C16[e], -S16[e]);
        float2 u = x[b + i];
        float2 vh = (e == 0) ? x[b + i + h] : cmulc(x[b + i + h], w);
        x[b + i] = cadd(u, vh);
        x[b + i + h] = csub(u, vh);
      }
}

template <int SGN>
__device__ __forceinline__ void midtw(float2* x, int lane) {
  const int rho[16] = {0, 8, 4, 12, 2, 10, 6, 14, 1, 9, 5, 13, 3, 11, 7, 15};
  float s, c;
  __sincosf((float)lane * 0.00613592315f, &s, &c);  // 2pi/1024
  float2 w = make_float2(c, SGN > 0 ? s : -s);
  float2 run = w;
  x[8] = cmul(x[8], run);
#pragma unroll
  for (int e = 2; e < 16; ++e) {
    run = cmul(run, w);
    x[rho[e]] = cmul(x[rho[e]], run);
  }
}

template <int SGN>
__device__ __forceinline__ void xlane_dif(float2* x, int lane) {
#pragma unroll
  for (int h = 32; h >= 1; h >>= 1) {
    const int e = (lane & (h - 1)) * (32 / h);
    float s, c;
    __sincosf((float)e * 0.09817477042f, &s, &c);  // 2pi/64
    float2 w = make_float2(c, SGN > 0 ? s : -s);
    const bool hi = (lane & h) != 0;
#pragma unroll
    for (int r = 0; r < 16; ++r) {
      float2 t = x[r];
      float2 p;
      p.x = __shfl_xor(t.x, h, 64);
      p.y = __shfl_xor(t.y, h, 64);
      x[r] = hi ? cmul(csub(p, t), w) : cadd(t, p);
    }
  }
}

template <int SGN>
__device__ __forceinline__ void wfft1024_dif(float2* x, int lane) {
  dft16_dif<SGN>(x);
  midtw<SGN>(x, lane);
  xlane_dif<SGN>(x, lane);
}

// -------- paired (two-row) variants: shared twiddles, 2x ILP per stage ----
template <int SGN>
__device__ __forceinline__ void midtw2(float2* x, float2* y, int lane) {
  const int rho[16] = {0, 8, 4, 12, 2, 10, 6, 14, 1, 9, 5, 13, 3, 11, 7, 15};
  float s, c;
  __sincosf((float)lane * 0.00613592315f, &s, &c);
  float2 w = make_float2(c, SGN > 0 ? s : -s);
  float2 run = w;
  x[8] = cmul(x[8], run);
  y[8] = cmul(y[8], run);
#pragma unroll
  for (int e = 2; e < 16; ++e) {
    run = cmul(run, w);
    x[rho[e]] = cmul(x[rho[e]], run);
    y[rho[e]] = cmul(y[rho[e]], run);
  }
}

__device__ __forceinline__ void midtw_inv2(float2* x, float2* y, int lane) {
  const int rho[16] = {0, 8, 4, 12, 2, 10, 6, 14, 1, 9, 5, 13, 3, 11, 7, 15};
  float s, c;
  __sincosf((float)lane * 0.00613592315f, &s, &c);
  float2 w = make_float2(c, -s);
  float2 run = w;
  x[8] = cmulc(x[8], run);
  y[8] = cmulc(y[8], run);
#pragma unroll
  for (int e = 2; e < 16; ++e) {
    run = cmul(run, w);
    x[rho[e]] = cmulc(x[rho[e]], run);
    y[rho[e]] = cmulc(y[rho[e]], run);
  }
}

template <int SGN>
__device__ __forceinline__ void xlane_dif2(float2* x, float2* y, int lane) {
#pragma unroll
  for (int h = 32; h >= 1; h >>= 1) {
    const int e = (lane & (h - 1)) * (32 / h);
    float s, c;
    __sincosf((float)e * 0.09817477042f, &s, &c);
    float2 w = make_float2(c, SGN > 0 ? s : -s);
    const bool hi = (lane & h) != 0;
#pragma unroll
    for (int r = 0; r < 16; ++r) {
      float2 t = x[r];
      float2 p;
      p.x = __shfl_xor(t.x, h, 64);
      p.y = __shfl_xor(t.y, h, 64);
      x[r] = hi ? cmul(csub(p, t), w) : cadd(t, p);
    }
#pragma unroll
    for (int r = 0; r < 16; ++r) {
      float2 t = y[r];
      float2 p;
      p.x = __shfl_xor(t.x, h, 64);
      p.y = __shfl_xor(t.y, h, 64);
      y[r] = hi ? cmul(csub(p, t), w) : cadd(t, p);
    }
  }
}

__device__ __forceinline__ void xlane_dit_inv2(float2* x, float2* y, int lane) {
#pragma unroll
  for (int h = 1; h <= 32; h <<= 1) {
    const int e = (lane & (h - 1)) * (32 / h);
    float s, c;
    __sincosf((float)e * 0.09817477042f, &s, &c);
    float2 w = make_float2(c, -s);
    const bool hi = (lane & h) != 0;
#pragma unroll
    for (int r = 0; r < 16; ++r) {
      float2 t = x[r];
      if (hi) t = cmulc(t, w);
      float2 p;
      p.x = __shfl_xor(t.x, h, 64);
      p.y = __shfl_xor(t.y, h, 64);
      x[r] = hi ? csub(p, t) : cadd(t, p);
    }
#pragma unroll
    for (int r = 0; r < 16; ++r) {
      float2 t = y[r];
      if (hi) t = cmulc(t, w);
      float2 p;
      p.x = __shfl_xor(t.x, h, 64);
      p.y = __shfl_xor(t.y, h, 64);
      y[r] = hi ? csub(p, t) : cadd(t, p);
    }
  }
}

template <int SGN>
__device__ __forceinline__ void wfft1024_dif2(float2* x, float2* y, int lane) {
  dft16_dif<SGN>(x);
  dft16_dif<SGN>(y);
  midtw2<SGN>(x, y, lane);
  xlane_dif2<SGN>(x, y, lane);
}
__device__ __forceinline__ void wfft1024_inv2(float2* x, float2* y, int lane) {
  xlane_dit_inv2(x, y, lane);
  midtw_inv2(x, y, lane);
  dit16_inv(x);
  dit16_inv(y);
}

// spectral gain; 1/N^2 folded in. alpha==1: cos(atan t) == rsqrt(1+t^2).
__device__ __forceinline__ float gainw(float re, float im, float alpha, bool a1) {
  float mag2 = re * re + im * im;
  float t = 0.5f * __logf(mag2 + 1e-20f);
  if (a1) return __builtin_amdgcn_rsqf(fmaf(t, t, 1.0f)) * (1.0f / 1048576.0f);
  return __cosf(alpha * atanf(t)) * (1.0f / 1048576.0f);
}

// ------------------------------------------------- k0: dtype detect + alpha
__global__ void k0_detect(const unsigned* __restrict__ q,
                          const void* __restrict__ alphap, int* __restrict__ flags) {
  __shared__ float smax[256];
  __shared__ int szero[256];
  int t = threadIdx.x;
  float mx = 0.f; int zc = 0;
  for (int i = t; i < 16384; i += 256) {
    unsigned w = q[i];
    unsigned lo = w & 0xFFFFu;
    float v = fabsf(__uint_as_float(lo << 16));
    if (!(v <= 1e30f)) v = 1e30f;
    mx = fmaxf(mx, v);
    zc += (lo == 0u);
  }
  smax[t] = mx; szero[t] = zc;
  __syncthreads();
  for (int s = 128; s > 0; s >>= 1) {
    if (t < s) { smax[t] = fmaxf(smax[t], smax[t + s]); szero[t] += szero[t + s]; }
    __syncthreads();
  }
  if (t == 0) {
    int isf32 = (smax[0] > 100.f) || (szero[0] > 12288);
    flags[0] = isf32;
    float alpha = isf32 ? *(const float*)alphap : bf2f(*(const short*)alphap);
    ((float*)flags)[1] = alpha;
  }
}

// ------------------------------------------------- k1: QKV projection (XCD-swizzled)
// All three outputs transposed: O[plane][d][s] (nothing reads row-major Q/K now).
__global__ __launch_bounds__(256) void k1_qkv(
    const void* __restrict__ x,
    const void* __restrict__ Wq, const void* __restrict__ bq,
    const void* __restrict__ Wk, const void* __restrict__ bk,
    const void* __restrict__ Wv, const void* __restrict__ bv,
    short* __restrict__ Qt, short* __restrict__ Kt, short* __restrict__ Vt,
    const int* __restrict__ flags)
{
  __shared__ __align__(16) char smem[128 * 136 * 2];
  short* As = (short*)smem;
  short* Bs = As + 128 * PITCH;
  short* Ct = (short*)smem;
  const int isf32 = flags[0];
  const int t = threadIdx.x;
  const int lb = blockIdx.x;
  const int m0 = ((lb & 7) * 4 + ((lb >> 3) & 3)) * 128;
  const int n0 = (lb >> 5) * 128;
  const int which = blockIdx.y;
  const void* __restrict__ W = (which == 0) ? Wq : (which == 1) ? Wk : Wv;
  const void* __restrict__ bias = (which == 0) ? bq : (which == 1) ? bk : bv;
  const int lane = t & 63, wvi = t >> 6;
  const int wr = wvi >> 1, wc = wvi & 1;
  const int lm = lane & 15, lq = lane >> 4;
  f32x4 acc[4][4] = {};

  for (int k0 = 0; k0 < 1024; k0 += 32) {
    __syncthreads();
#pragma unroll
    for (int i = 0; i < 2; ++i) {
      int l = t + i * 256;
      int row = l >> 2, kk = (l & 3) << 3;
      *(short8*)&As[row * PITCH + kk] = ld8(x, (size_t)(m0 + row) * 1024 + k0 + kk, isf32);
      *(short8*)&Bs[row * PITCH + kk] = ld8(W, (size_t)(n0 + row) * 1024 + k0 + kk, isf32);
    }
    __syncthreads();
    short8 af[4], bf[4];
#pragma unroll
    for (int a = 0; a < 4; ++a) af[a] = *(const short8*)&As[(wr * 64 + a * 16 + lm) * PITCH + lq * 8];
#pragma unroll
    for (int b = 0; b < 4; ++b) bf[b] = *(const short8*)&Bs[(wc * 64 + b * 16 + lm) * PITCH + lq * 8];
#pragma unroll
    for (int a = 0; a < 4; ++a)
#pragma unroll
      for (int b = 0; b < 4; ++b)
        acc[a][b] = __builtin_amdgcn_mfma_f32_16x16x32_bf16(af[a], bf[b], acc[a][b], 0, 0, 0);
  }

  __syncthreads();
#pragma unroll
  for (int a = 0; a < 4; ++a)
#pragma unroll
    for (int b = 0; b < 4; ++b) {
      int col = wc * 64 + b * 16 + lm;
      float bv_ = ldf(bias, n0 + col, isf32);
#pragma unroll
      for (int r = 0; r < 4; ++r) {
        int row = wr * 64 + a * 16 + lq * 4 + r;
        Ct[row * 136 + col] = f2bf(acc[a][b][r] + bv_);
      }
    }
  __syncthreads();

  short* __restrict__ O = (which == 0) ? Qt : (which == 1) ? Kt : Vt;
#pragma unroll
  for (int j = 0; j < 8; ++j) {
    int id = t + j * 256;
    int d128 = id & 127, sg = (id >> 7) * 8;
    short vals[8];
#pragma unroll
    for (int i = 0; i < 8; ++i) vals[i] = Ct[(sg + i) * 136 + d128];
    int col = n0 + d128;
    int h = col >> 6, d = col & 63;
    int bb = m0 >> 10, sbase = (m0 & 1023) + sg;
    *(short8*)&O[(((size_t)(bb * 16 + h)) << 16) + ((size_t)d << 10) + sbase] = *(short8*)vals;
  }
}

// ------------------------------------------------- kA: column FFTs of Q and K
// Q side (blocks 0..7): pair of d-columns per wave, scale 1/8 folded in,
//   output Qhat[zl*64+d][slot] in SCRAMBLED-u slot order (linear (l,r) write).
// K side (blocks 8..15): one d-pair per wave, wave-private LDS scatter to
//   natural order, Hermitian split, output Khat[zl*64+d][v] v=0..512 natural.
__global__ __launch_bounds__(256) void kA_qkfft(
    const short* __restrict__ Qt, const short* __restrict__ Kt,
    __half2* __restrict__ Qhat, __half2* __restrict__ Khat, int bh0)
{
  __shared__ float2 sbuf[4][1024];
  const int lane = threadIdx.x & 63, w = threadIdx.x >> 6;
  const int zl = blockIdx.y;
  const int z = bh0 + zl;
  const int bx = blockIdx.x;
  if (bx < 8) {
    const short* qp = Qt + ((size_t)z << 16);
    const int d0 = bx * 8 + w * 2;
    float2 x[16], y[16];
#pragma unroll
    for (int j = 0; j < 16; ++j) {
      x[j] = make_float2(0.125f * bf2f(qp[(d0 << 10) + lane + 64 * j]), 0.f);
      y[j] = make_float2(0.125f * bf2f(qp[((d0 + 1) << 10) + lane + 64 * j]), 0.f);
    }
    wfft1024_dif2<-1>(x, y, lane);
    __half2* o0 = Qhat + (((size_t)(zl * 64 + d0)) << 10);
    __half2* o1 = o0 + 1024;
#pragma unroll
    for (int r = 0; r < 16; ++r) {
      o0[lane + 64 * r] = __float22half2_rn(x[r]);
      o1[lane + 64 * r] = __float22half2_rn(y[r]);
    }
  } else {
    const short* kp = Kt + ((size_t)z << 16);
    const int p = (bx - 8) * 4 + w;
    const int d0 = 2 * p;
    float2 x[16];
#pragma unroll
    for (int j = 0; j < 16; ++j)
      x[j] = make_float2(bf2f(kp[(d0 << 10) + lane + 64 * j]),
                         bf2f(kp[((d0 + 1) << 10) + lane + 64 * j]));
    wfft1024_dif<-1>(x, lane);
    const int rho[16] = {0, 8, 4, 12, 2, 10, 6, 14, 1, 9, 5, 13, 3, 11, 7, 15};
    const int bl6 = ((lane & 1) << 5) | ((lane & 2) << 3) | ((lane & 4) << 1) |
                    ((lane & 8) >> 1) | ((lane & 16) >> 3) | ((lane & 32) >> 5);
    float2* buf = sbuf[w];
#pragma unroll
    for (int r = 0; r < 16; ++r) buf[rho[r] + 16 * bl6] = x[r];
    __half2* o0 = Khat + (size_t)(zl * 64 + d0) * 520;
    __half2* o1 = o0 + 520;
#pragma unroll 1
    for (int jj = 0; jj < 9; ++jj) {
      int v = lane + 64 * jj;
      if (v <= 512) {
        float2 A = buf[v], B = buf[(1024 - v) & 1023];
        // K1 = (Z + conj(Z~))/2 ; K2 = (Z - conj(Z~))/(2i)
        o0[v] = __float22half2_rn(make_float2((A.x + B.x) * 0.5f, (A.y - B.y) * 0.5f));
        o1[v] = __float22half2_rn(make_float2((A.y + B.y) * 0.5f, (B.x - A.x) * 0.5f));
      }
    }
  }
}

// ------------------------------------------------- kB: F2D = Khat x Qhat^T + gain
// C[v][u-slot], M=64 (v), N=128 (u), K=64 (d). fp16 MFMA, f32 accum.
// Cre = Are*Bre - Aim*Bim ; Cim = Are*Bim + Aim*Bre (Aim negated in-reg).
__global__ __launch_bounds__(256) void kB_specmm(
    const __half2* __restrict__ Qhat, const __half2* __restrict__ Khat,
    __half2* __restrict__ Ct, const int* __restrict__ flags)
{
  __shared__ unsigned short Are[64][72], Aim[64][72], Bre[128][72], Bim[128][72];
  const int t = threadIdx.x;
  const int u0 = blockIdx.x * 128;
  const int v0 = blockIdx.y * 64;
  const int zl = blockIdx.z;
  const float alpha = ((const float*)flags)[1];
  const bool a1 = (alpha == 1.0f);
  {
    const int d = t >> 2;
    // A: Khat[d][520] rows v0..v0+63 (clamped; garbage rows are store-masked)
    const ushort2* src = (const ushort2*)(Khat + (size_t)(zl * 64 + d) * 520);
    int vb = (t & 3) * 16;
#pragma unroll
    for (int j = 0; j < 16; ++j) {
      int v = v0 + vb + j;
      if (v > 519) v = 519;
      ushort2 e = src[v];
      int row = vb + j;
      int dc = d ^ (((row >> 4) & 3) << 4);  // bank-spread swizzle
      Are[row][dc] = e.x;
      Aim[row][dc] = e.y;
    }
    // B: Qhat[d][1024] slots u0..u0+127
    const ushort2* srcb = (const ushort2*)(Qhat + (((size_t)(zl * 64 + d)) << 10) + u0);
    int ub = (t & 3) * 32;
#pragma unroll
    for (int j = 0; j < 32; ++j) {
      ushort2 e = srcb[ub + j];
      int row = ub + j;
      int dc = d ^ (((row >> 5) & 3) << 4);
      Bre[row][dc] = e.x;
      Bim[row][dc] = e.y;
    }
  }
  __syncthreads();

  const int lane = t & 63, wc = t >> 6;
  const int lm = lane & 15, lq = lane >> 4;
  f32x4 cre[4][2] = {}, cim[4][2] = {};
#pragma unroll
  for (int ks = 0; ks < 2; ++ks) {
    half8 ar[4], ai[4], aiN[4], br[2], bi[2];
#pragma unroll
    for (int a = 0; a < 4; ++a) {
      int dc = (ks * 32 + lq * 8) ^ ((a & 3) << 4);
      ar[a] = *(const half8*)&Are[a * 16 + lm][dc];
      ai[a] = *(const half8*)&Aim[a * 16 + lm][dc];
      int4 tm = *(int4*)&ai[a];
      tm.x ^= 0x80008000; tm.y ^= 0x80008000; tm.z ^= 0x80008000; tm.w ^= 0x80008000;
      aiN[a] = *(half8*)&tm;
    }
#pragma unroll
    for (int n = 0; n < 2; ++n) {
      int dc = (ks * 32 + lq * 8) ^ ((wc & 3) << 4);
      br[n] = *(const half8*)&Bre[wc * 32 + n * 16 + lm][dc];
      bi[n] = *(const half8*)&Bim[wc * 32 + n * 16 + lm][dc];
    }
#pragma unroll
    for (int a = 0; a < 4; ++a)
#pragma unroll
      for (int n = 0; n < 2; ++n) {
        cre[a][n] = __builtin_amdgcn_mfma_f32_16x16x32_f16(ar[a], br[n], cre[a][n], 0, 0, 0);
        cre[a][n] = __builtin_amdgcn_mfma_f32_16x16x32_f16(aiN[a], bi[n], cre[a][n], 0, 0, 0);
        cim[a][n] = __builtin_amdgcn_mfma_f32_16x16x32_f16(ar[a], bi[n], cim[a][n], 0, 0, 0);
        cim[a][n] = __builtin_amdgcn_mfma_f32_16x16x32_f16(ai[a], br[n], cim[a][n], 0, 0, 0);
      }
  }

  __half2* outp = Ct + (size_t)zl * 513 * 1024 + u0 + wc * 32;
#pragma unroll
  for (int a = 0; a < 4; ++a)
#pragma unroll
    for (int r = 0; r < 4; ++r) {
      int v = v0 + a * 16 + lq * 4 + r;
      if (v < 513) {
#pragma unroll
        for (int n = 0; n < 2; ++n) {
          float re = cre[a][n][r], im = cim[a][n][r];
          float wf = gainw(re, im, alpha, a1);
          outp[(size_t)v * 1024 + n * 16 + lm] =
              __float22half2_rn(make_float2(re * wf, im * wf));
        }
      }
    }
}

// ------------------------------------------------- k4: inverse u-FFT (in place)
// Reads F~[v][u-slot] (scrambled-u), writes G[v][q] natural. Two rows/wave.
__global__ __launch_bounds__(256) void k4_invfft(__half2* __restrict__ Ct)
{
  const int lane = threadIdx.x & 63;
  const int w = threadIdx.x >> 6;
  const int gv0 = blockIdx.x * 8 + w * 2;
  if (gv0 > 512) return;
  const bool has1 = (gv0 + 1 <= 512);
  __half2* __restrict__ row0 = Ct + (size_t)blockIdx.y * 513 * 1024 + ((size_t)gv0 << 10);
  __half2* __restrict__ row1 = row0 + 1024;
  float2 x[16], y[16];
#pragma unroll
  for (int j = 0; j < 16; ++j) x[j] = __half22float2(row0[lane + 64 * j]);
  if (has1) {
#pragma unroll
    for (int j = 0; j < 16; ++j) y[j] = __half22float2(row1[lane + 64 * j]);
  } else {
#pragma unroll
    for (int j = 0; j < 16; ++j) y[j] = make_float2(0.f, 0.f);
  }
  wfft1024_inv2(x, y, lane);
#pragma unroll
  for (int j = 0; j < 16; ++j) row0[lane + 64 * j] = __float22half2_rn(x[j]);
  if (has1) {
#pragma unroll
    for (int j = 0; j < 16; ++j) row1[lane + 64 * j] = __float22half2_rn(y[j]);
  }
}

// ------------------------------------------------- k56: inverse row FFT + softmax + PV
__global__ __launch_bounds__(256) void k56_softmax_av(
    const __half2* __restrict__ Ct, const short* __restrict__ Vt,
    short* __restrict__ ctx, int bh0)
{
  __shared__ __align__(16) char GP[33280];
  const int tid = threadIdx.x;
  const int q0 = blockIdx.x * 16, z = blockIdx.y;
  const int lane = tid & 63, w = tid >> 6;
  const int lm = lane & 15, lq = lane >> 4;
  const __half2* __restrict__ in = Ct + (size_t)z * 513 * 1024;
#define GROW(m) ((__half2*)(GP + 448 + (m) * 2052))
  for (int id = tid; id < 2052; id += 256) {
    int v = id >> 2, qq = (id & 3) * 4;
    int4 o = *(const int4*)&in[(size_t)v * 1024 + q0 + qq];
    __half2* op = (__half2*)&o;
#pragma unroll
    for (int i = 0; i < 4; ++i) GROW(qq + i)[v] = op[i];
  }
  short* P = (short*)GP;  // row m at m*1040 shorts
  const int bl6 = ((lane & 1) << 5) | ((lane & 2) << 3) | ((lane & 4) << 1) |
                  ((lane & 8) >> 1) | ((lane & 16) >> 3) | ((lane & 32) >> 5);
  __syncthreads();  // Gbuf ready

#pragma unroll 1
  for (int round = 0; round < 2; ++round) {
    const int p = w + round * 4;
    const __half2* g1 = GROW(2 * p);
    const __half2* g2 = GROW(2 * p + 1);
    float2 x[16];
#pragma unroll
    for (int j = 0; j < 16; ++j) {
      int v = lane + 64 * j;
      float2 a, b;
      if (v <= 512) {
        a = __half22float2(g1[v]);
        b = __half22float2(g2[v]);
      } else {
        int v2 = 1024 - v;
        float2 aa = __half22float2(g1[v2]), bb = __half22float2(g2[v2]);
        a = make_float2(aa.x, -aa.y);
        b = make_float2(bb.x, -bb.y);
      }
      x[j] = make_float2(a.x - b.y, a.y + b.x);
    }

    wfft1024_dif<1>(x, lane);  // sum_v z W^{+vk}: Re = row 2p, Im = row 2p+1

    float m1 = -3.4e38f, m2 = -3.4e38f;
#pragma unroll
    for (int j = 0; j < 16; ++j) { m1 = fmaxf(m1, x[j].x); m2 = fmaxf(m2, x[j].y); }
#pragma unroll
    for (int s = 32; s > 0; s >>= 1) {
      m1 = fmaxf(m1, __shfl_xor(m1, s, 64));
      m2 = fmaxf(m2, __shfl_xor(m2, s, 64));
    }
    float s1 = 0.f, s2 = 0.f;
#pragma unroll
    for (int j = 0; j < 16; ++j) {
      float e1 = __expf(x[j].x - m1), e2 = __expf(x[j].y - m2);
      x[j] = make_float2(e1, e2);
      s1 += e1; s2 += e2;
    }
#pragma unroll
    for (int s = 32; s > 0; s >>= 1) {
      s1 += __shfl_xor(s1, s, 64);
      s2 += __shfl_xor(s2, s, 64);
    }
    float inv1 = 1.0f / s1, inv2 = 1.0f / s2;

    __syncthreads();  // ALL G reads of this round done before ANY P writes

    const int rho[16] = {0, 8, 4, 12, 2, 10, 6, 14, 1, 9, 5, 13, 3, 11, 7, 15};
#pragma unroll
    for (int j = 0; j < 16; ++j) {
      int k = rho[j] + 16 * bl6;
      P[(2 * p) * 1040 + k]     = f2bf(x[j].x * inv1);
      P[(2 * p + 1) * 1040 + k] = f2bf(x[j].y * inv2);
    }
  }
  __syncthreads();  // P complete

  const short* __restrict__ Vp = Vt + ((size_t)(bh0 + z) << 16);
  f32x4 acc[4] = {};
#pragma unroll
  for (int ks = 0; ks < 8; ++ks) {
    int k0 = w * 256 + ks * 32;
    short8 a0 = *(const short8*)&P[lm * 1040 + k0 + lq * 8];
#pragma unroll
    for (int b = 0; b < 4; ++b) {
      short8 bv = *(const short8*)&Vp[(size_t)(b * 16 + lm) * 1024 + k0 + lq * 8];
      acc[b] = __builtin_amdgcn_mfma_f32_16x16x32_bf16(a0, bv, acc[b], 0, 0, 0);
    }
  }
  __syncthreads();  // all P reads done; reuse GP for reduction
  float* red = (float*)GP;
#pragma unroll
  for (int b = 0; b < 4; ++b)
#pragma unroll
    for (int r = 0; r < 4; ++r)
      red[(w * 16 + lq * 4 + r) * 64 + b * 16 + lm] = acc[b][r];
  __syncthreads();
  {
    int q = tid >> 4, d0 = (tid & 15) * 4;
    float s0 = 0.f, s1 = 0.f, s2 = 0.f, s3 = 0.f;
#pragma unroll
    for (int ww = 0; ww < 4; ++ww) {
      const float* rr = &red[(ww * 16 + q) * 64 + d0];
      s0 += rr[0]; s1 += rr[1]; s2 += rr[2]; s3 += rr[3];
    }
    short o4[4] = {f2bf(s0), f2bf(s1), f2bf(s2), f2bf(s3)};
    *(int2*)&ctx[(((size_t)(bh0 + z)) << 16) + (size_t)(q0 + q) * 64 + d0] = *(int2*)o4;
  }
#undef GROW
}

// ------------------------------------------------- k7: out = ctx @ Wo^T + bo (XCD-swizzled)
__global__ __launch_bounds__(256) void k7_out(
    const short* __restrict__ ctx, const void* __restrict__ Wo,
    const void* __restrict__ bo, void* __restrict__ out,
    const int* __restrict__ flags)
{
  __shared__ __align__(16) char smem[128 * 136 * 2];
  short* As = (short*)smem;
  short* Bs = As + 128 * PITCH;
  short* Ct = (short*)smem;
  const int isf32 = flags[0];
  const int t = threadIdx.x;
  const int lb = blockIdx.x;
  const int m0 = ((lb & 7) * 4 + ((lb >> 3) & 3)) * 128;
  const int n0 = (lb >> 5) * 128;
  const int lane = t & 63, wvi = t >> 6;
  const int wr = wvi >> 1, wc = wvi & 1;
  const int lm = lane & 15, lq = lane >> 4;
  f32x4 acc[4][4] = {};

  for (int k0 = 0; k0 < 1024; k0 += 32) {
    __syncthreads();
#pragma unroll
    for (int i = 0; i < 2; ++i) {
      int l = t + i * 256;
      int row = l >> 2, kk = (l & 3) << 3;
      int n = m0 + row, e = k0 + kk;
      size_t aaddr = (((size_t)((n >> 10) * 16 + (e >> 6))) << 16) + (size_t)((n & 1023) << 6) + (e & 63);
      *(int4*)&As[row * PITCH + kk] = *(const int4*)&ctx[aaddr];
      *(short8*)&Bs[row * PITCH + kk] = ld8(Wo, (size_t)(n0 + row) * 1024 + e, isf32);
    }
    __syncthreads();
    short8 af[4], bf[4];
#pragma unroll
    for (int a = 0; a < 4; ++a) af[a] = *(const short8*)&As[(wr * 64 + a * 16 + lm) * PITCH + lq * 8];
#pragma unroll
    for (int b = 0; b < 4; ++b) bf[b] = *(const short8*)&Bs[(wc * 64 + b * 16 + lm) * PITCH + lq * 8];
#pragma unroll
    for (int a = 0; a < 4; ++a)
#pragma unroll
      for (int b = 0; b < 4; ++b)
        acc[a][b] = __builtin_amdgcn_mfma_f32_16x16x32_bf16(af[a], bf[b], acc[a][b], 0, 0, 0);
  }

  if (isf32) {
#pragma unroll
    for (int a = 0; a < 4; ++a)
#pragma unroll
      for (int b = 0; b < 4; ++b) {
        int col = n0 + wc * 64 + b * 16 + lm;
        float bo_ = ldf(bo, col, 1);
#pragma unroll
        for (int r = 0; r < 4; ++r) {
          int row = m0 + wr * 64 + a * 16 + lq * 4 + r;
          ((float*)out)[(size_t)row * 1024 + col] = acc[a][b][r] + bo_;
        }
      }
    return;
  }
  __syncthreads();
#pragma unroll
  for (int a = 0; a < 4; ++a)
#pragma unroll
    for (int b = 0; b < 4; ++b) {
      int col = wc * 64 + b * 16 + lm;
      float bo_ = ldf(bo, n0 + col, 0);
#pragma unroll
      for (int r = 0; r < 4; ++r) {
        int row = wr * 64 + a * 16 + lq * 4 + r;
        Ct[row * 136 + col] = f2bf(acc[a][b][r] + bo_);
      }
    }
  __syncthreads();
#pragma unroll
  for (int j = 0; j < 8; ++j) {
    int id = t + j * 256;
    int row = id >> 4, c16 = (id & 15) * 8;
    short8 v = *(const short8*)&Ct[row * 136 + c16];
    *(short8*)&((short*)out)[(size_t)(m0 + row) * 1024 + n0 + c16] = v;
  }
}

// ------------------------------------------------- launch
extern "C" void kernel_launch(void* const* d_in, const int* in_sizes, int n_in,
                              void* d_out, int out_size, void* d_ws, size_t ws_size,
                              hipStream_t stream)
{
  const void* x  = d_in[0];
  const void* Wq = d_in[1];
  const void* bq = d_in[2];
  const void* Wk = d_in[3];
  const void* bk = d_in[4];
  const void* Wv = d_in[5];
  const void* bv = d_in[6];
  const void* Wo = d_in[7];
  const void* bo = d_in[8];
  const void* alphap = d_in[9];
  char* ws = (char*)d_ws;

  // 8-plane chunks. Byte offsets:
  const size_t CT_OFF = (size_t)32u << 20;                    // Ct: 8*513*1024*4 = 16,809,984
  const size_t QH_OFF = CT_OFF + (size_t)8 * 513 * 1024 * 4;  // Qhat: 8*64*1024*4 = 2,097,152
  const size_t KH_OFF = QH_OFF + (size_t)8 * 64 * 1024 * 4;   // Khat: 8*64*520*4 = 1,064,960
  const size_t FL_OFF = KH_OFF + (size_t)8 * 64 * 520 * 4;

  short*   Qt   = (short*)(ws);
  short*   Kt   = (short*)(ws + ((size_t)8u << 20));
  short*   Vt   = (short*)(ws + ((size_t)16u << 20));
  short*   ctx  = (short*)(ws + ((size_t)24u << 20));
  __half2* Ct   = (__half2*)(ws + CT_OFF);
  __half2* Qhat = (__half2*)(ws + QH_OFF);
  __half2* Khat = (__half2*)(ws + KH_OFF);
  int*     flags = (int*)(ws + FL_OFF);

  k0_detect<<<1, 256, 0, stream>>>((const unsigned*)x, alphap, flags);
  k1_qkv<<<dim3(256, 3), 256, 0, stream>>>(x, Wq, bq, Wk, bk, Wv, bv, Qt, Kt, Vt, flags);
  for (int c = 0; c < 8; ++c) {
    int bh0 = c * 8;
    kA_qkfft<<<dim3(16, 8), 256, 0, stream>>>(Qt, Kt, Qhat, Khat, bh0);
    kB_specmm<<<dim3(8, 9, 8), 256, 0, stream>>>(Qhat, Khat, Ct, flags);
    k4_invfft<<<dim3(65, 8), 256, 0, stream>>>(Ct);
    k56_softmax_av<<<dim3(64, 8), 256, 0, stream>>>(Ct, Vt, ctx, bh0);
  }
  k7_out<<<256, 256, 0, stream>>>(ctx, Wo, bo, d_out, flags);
}

// Round 4
// 799.806 us; speedup vs baseline: 1.2464x; 1.1326x over previous
//
#include <hip/hip_runtime.h>
#include <hip/hip_fp16.h>

// SpectralAttention: B=4, S=1024, E=1024, H=16, HD=64.
// Identity: real(ifft2(F*exp(i*phi))) == ifft2(F * cos(phi)) for real scores
// => real spectral gain, Hermitian half-spectrum (v=0..512).
//
// Round-9: occupancy restructure.
//  - k56: 512 threads / 8 waves, SINGLE round (each wave owns one p-pair).
//  - kA: ONE dispatch for all 64 planes (grid 32x64, 2-wave blocks).
//  - Workspace overlay: per-chunk Ct reuses the dead Qt/Kt region after kA.
//  - kB/k4/k1/k7 unchanged.
//
// Workspace (~59.9 MiB), timeline-safe overlay:
//   [0..8M)    Qt   (k1 -> kA)          \ overlaid by
//   [8..16M)   Kt   (k1 -> kA)          / Ct 16.81M (kB -> k4 -> k56, per chunk)
//   [17..25M)  Vt   | [25..33M) ctx | [33..49M) Qhat-all | [49..58.4M) Khat-all | flags

typedef __attribute__((ext_vector_type(8))) short short8;
typedef __attribute__((ext_vector_type(8))) _Float16 half8;
typedef __attribute__((ext_vector_type(4))) float f32x4;

#define PITCH 40

__device__ __forceinline__ float bf2f(short v) {
  return __uint_as_float(((unsigned)(unsigned short)v) << 16);
}
__device__ __forceinline__ short f2bf(float f) {
  unsigned u = __float_as_uint(f);
  u += 0x7FFFu + ((u >> 16) & 1u);  // RNE
  return (short)(u >> 16);
}

__device__ __forceinline__ short8 ld8(const void* p, size_t idx, int isf32) {
  short8 r;
  if (isf32) {
    const float* f = (const float*)p + idx;
    float4 a = *(const float4*)f;
    float4 b = *(const float4*)(f + 4);
    r[0] = f2bf(a.x); r[1] = f2bf(a.y); r[2] = f2bf(a.z); r[3] = f2bf(a.w);
    r[4] = f2bf(b.x); r[5] = f2bf(b.y); r[6] = f2bf(b.z); r[7] = f2bf(b.w);
  } else {
    r = *(const short8*)((const short*)p + idx);
  }
  return r;
}
__device__ __forceinline__ float ldf(const void* p, int idx, int isf32) {
  return isf32 ? ((const float*)p)[idx] : bf2f(((const short*)p)[idx]);
}

__device__ __forceinline__ float2 cmul(float2 a, float2 b) {
  return make_float2(a.x * b.x - a.y * b.y, a.x * b.y + a.y * b.x);
}
__device__ __forceinline__ float2 cmulc(float2 a, float2 b) {  // a * conj(b)
  return make_float2(a.x * b.x + a.y * b.y, a.y * b.x - a.x * b.y);
}
__device__ __forceinline__ float2 cadd(float2 a, float2 b) {
  return make_float2(a.x + b.x, a.y + b.y);
}
__device__ __forceinline__ float2 csub(float2 a, float2 b) {
  return make_float2(a.x - b.x, a.y - b.y);
}

// ================== wave-register 1024-pt FFT (16 in-reg x 64 cross-lane) ==
// Layout: lane l holds z[l + 64*j], j=0..15 (n1 = lane, n2 = reg).
// Forward DIF output: (lane l, reg r) holds F[bitrev4(r) + 16*bitrev6(l)].
// wfft1024_dif<-1> = true DFT (W^-), <+1> = unnormalized inverse (W^+).
// wfft1024_inv2 = exact stage-mirror of dif<-1>; dif(-1) o inv = 1024*I.

template <int SGN>
__device__ __forceinline__ void dft16_dif(float2* x) {
  const float C16[8] = {1.f, 0.92387953f, 0.70710678f, 0.38268343f,
                        0.f, -0.38268343f, -0.70710678f, -0.92387953f};
  const float S16[8] = {0.f, 0.38268343f, 0.70710678f, 0.92387953f,
                        1.f, 0.92387953f, 0.70710678f, 0.38268343f};
#pragma unroll
  for (int h = 8; h >= 1; h >>= 1)
#pragma unroll
    for (int b = 0; b < 16; b += 2 * h)
#pragma unroll
      for (int i = 0; i < h; ++i) {
        const int e = i * (8 / h);
        float2 u = x[b + i], v = x[b + i + h];
        x[b + i] = cadd(u, v);
        float2 d = csub(u, v);
        float2 w = make_float2(C16[e], SGN > 0 ? S16[e] : -S16[e]);
        x[b + i + h] = (e == 0) ? d : cmul(d, w);
      }
}

__device__ __forceinline__ void dit16_inv(float2* x) {
  const float C16[8] = {1.f, 0.92387953f, 0.70710678f, 0.38268343f,
                        0.f, -0.38268343f, -0.70710678f, -0.92387953f};
  const float S16[8] = {0.f, 0.38268343f, 0.70710678f, 0.92387953f,
                        1.f, 0.92387953f, 0.70710678f, 0.38268343f};
#pragma unroll
  for (int h = 1; h <= 8; h <<= 1)
#pragma unroll
    for (int b = 0; b < 16; b += 2 * h)
#pragma unroll
      for (int i = 0; i < h; ++i) {
        const int e = i * (8 / h);
        float2 w = make_float2(C16[e], -S16[e]);
        float2 u = x[b + i];
        float2 vh = (e == 0) ? x[b + i + h] : cmulc(x[b + i + h], w);
        x[b + i] = cadd(u, vh);
        x[b + i + h] = csub(u, vh);
      }
}

template <int SGN>
__device__ __forceinline__ void midtw(float2* x, int lane) {
  const int rho[16] = {0, 8, 4, 12, 2, 10, 6, 14, 1, 9, 5, 13, 3, 11, 7, 15};
  float s, c;
  __sincosf((float)lane * 0.00613592315f, &s, &c);  // 2pi/1024
  float2 w = make_float2(c, SGN > 0 ? s : -s);
  float2 run = w;
  x[8] = cmul(x[8], run);
#pragma unroll
  for (int e = 2; e < 16; ++e) {
    run = cmul(run, w);
    x[rho[e]] = cmul(x[rho[e]], run);
  }
}

template <int SGN>
__device__ __forceinline__ void xlane_dif(float2* x, int lane) {
#pragma unroll
  for (int h = 32; h >= 1; h >>= 1) {
    const int e = (lane & (h - 1)) * (32 / h);
    float s, c;
    __sincosf((float)e * 0.09817477042f, &s, &c);  // 2pi/64
    float2 w = make_float2(c, SGN > 0 ? s : -s);
    const bool hi = (lane & h) != 0;
#pragma unroll
    for (int r = 0; r < 16; ++r) {
      float2 t = x[r];
      float2 p;
      p.x = __shfl_xor(t.x, h, 64);
      p.y = __shfl_xor(t.y, h, 64);
      x[r] = hi ? cmul(csub(p, t), w) : cadd(t, p);
    }
  }
}

template <int SGN>
__device__ __forceinline__ void wfft1024_dif(float2* x, int lane) {
  dft16_dif<SGN>(x);
  midtw<SGN>(x, lane);
  xlane_dif<SGN>(x, lane);
}

// -------- paired (two-row) variants: shared twiddles, 2x ILP per stage ----
template <int SGN>
__device__ __forceinline__ void midtw2(float2* x, float2* y, int lane) {
  const int rho[16] = {0, 8, 4, 12, 2, 10, 6, 14, 1, 9, 5, 13, 3, 11, 7, 15};
  float s, c;
  __sincosf((float)lane * 0.00613592315f, &s, &c);
  float2 w = make_float2(c, SGN > 0 ? s : -s);
  float2 run = w;
  x[8] = cmul(x[8], run);
  y[8] = cmul(y[8], run);
#pragma unroll
  for (int e = 2; e < 16; ++e) {
    run = cmul(run, w);
    x[rho[e]] = cmul(x[rho[e]], run);
    y[rho[e]] = cmul(y[rho[e]], run);
  }
}

__device__ __forceinline__ void midtw_inv2(float2* x, float2* y, int lane) {
  const int rho[16] = {0, 8, 4, 12, 2, 10, 6, 14, 1, 9, 5, 13, 3, 11, 7, 15};
  float s, c;
  __sincosf((float)lane * 0.00613592315f, &s, &c);
  float2 w = make_float2(c, -s);
  float2 run = w;
  x[8] = cmulc(x[8], run);
  y[8] = cmulc(y[8], run);
#pragma unroll
  for (int e = 2; e < 16; ++e) {
    run = cmul(run, w);
    x[rho[e]] = cmulc(x[rho[e]], run);
    y[rho[e]] = cmulc(y[rho[e]], run);
  }
}

template <int SGN>
__device__ __forceinline__ void xlane_dif2(float2* x, float2* y, int lane) {
#pragma unroll
  for (int h = 32; h >= 1; h >>= 1) {
    const int e = (lane & (h - 1)) * (32 / h);
    float s, c;
    __sincosf((float)e * 0.09817477042f, &s, &c);
    float2 w = make_float2(c, SGN > 0 ? s : -s);
    const bool hi = (lane & h) != 0;
#pragma unroll
    for (int r = 0; r < 16; ++r) {
      float2 t = x[r];
      float2 p;
      p.x = __shfl_xor(t.x, h, 64);
      p.y = __shfl_xor(t.y, h, 64);
      x[r] = hi ? cmul(csub(p, t), w) : cadd(t, p);
    }
#pragma unroll
    for (int r = 0; r < 16; ++r) {
      float2 t = y[r];
      float2 p;
      p.x = __shfl_xor(t.x, h, 64);
      p.y = __shfl_xor(t.y, h, 64);
      y[r] = hi ? cmul(csub(p, t), w) : cadd(t, p);
    }
  }
}

__device__ __forceinline__ void xlane_dit_inv2(float2* x, float2* y, int lane) {
#pragma unroll
  for (int h = 1; h <= 32; h <<= 1) {
    const int e = (lane & (h - 1)) * (32 / h);
    float s, c;
    __sincosf((float)e * 0.09817477042f, &s, &c);
    float2 w = make_float2(c, -s);
    const bool hi = (lane & h) != 0;
#pragma unroll
    for (int r = 0; r < 16; ++r) {
      float2 t = x[r];
      if (hi) t = cmulc(t, w);
      float2 p;
      p.x = __shfl_xor(t.x, h, 64);
      p.y = __shfl_xor(t.y, h, 64);
      x[r] = hi ? csub(p, t) : cadd(t, p);
    }
#pragma unroll
    for (int r = 0; r < 16; ++r) {
      float2 t = y[r];
      if (hi) t = cmulc(t, w);
      float2 p;
      p.x = __shfl_xor(t.x, h, 64);
      p.y = __shfl_xor(t.y, h, 64);
      y[r] = hi ? csub(p, t) : cadd(t, p);
    }
  }
}

template <int SGN>
__device__ __forceinline__ void wfft1024_dif2(float2* x, float2* y, int lane) {
  dft16_dif<SGN>(x);
  dft16_dif<SGN>(y);
  midtw2<SGN>(x, y, lane);
  xlane_dif2<SGN>(x, y, lane);
}
__device__ __forceinline__ void wfft1024_inv2(float2* x, float2* y, int lane) {
  xlane_dit_inv2(x, y, lane);
  midtw_inv2(x, y, lane);
  dit16_inv(x);
  dit16_inv(y);
}

// spectral gain; 1/N^2 folded in. alpha==1: cos(atan t) == rsqrt(1+t^2).
__device__ __forceinline__ float gainw(float re, float im, float alpha, bool a1) {
  float mag2 = re * re + im * im;
  float t = 0.5f * __logf(mag2 + 1e-20f);
  if (a1) return __builtin_amdgcn_rsqf(fmaf(t, t, 1.0f)) * (1.0f / 1048576.0f);
  return __cosf(alpha * atanf(t)) * (1.0f / 1048576.0f);
}

// ------------------------------------------------- k0: dtype detect + alpha
__global__ void k0_detect(const unsigned* __restrict__ q,
                          const void* __restrict__ alphap, int* __restrict__ flags) {
  __shared__ float smax[256];
  __shared__ int szero[256];
  int t = threadIdx.x;
  float mx = 0.f; int zc = 0;
  for (int i = t; i < 16384; i += 256) {
    unsigned w = q[i];
    unsigned lo = w & 0xFFFFu;
    float v = fabsf(__uint_as_float(lo << 16));
    if (!(v <= 1e30f)) v = 1e30f;
    mx = fmaxf(mx, v);
    zc += (lo == 0u);
  }
  smax[t] = mx; szero[t] = zc;
  __syncthreads();
  for (int s = 128; s > 0; s >>= 1) {
    if (t < s) { smax[t] = fmaxf(smax[t], smax[t + s]); szero[t] += szero[t + s]; }
    __syncthreads();
  }
  if (t == 0) {
    int isf32 = (smax[0] > 100.f) || (szero[0] > 12288);
    flags[0] = isf32;
    float alpha = isf32 ? *(const float*)alphap : bf2f(*(const short*)alphap);
    ((float*)flags)[1] = alpha;
  }
}

// ------------------------------------------------- k1: QKV projection (XCD-swizzled)
// All three outputs transposed: O[plane][d][s].
__global__ __launch_bounds__(256) void k1_qkv(
    const void* __restrict__ x,
    const void* __restrict__ Wq, const void* __restrict__ bq,
    const void* __restrict__ Wk, const void* __restrict__ bk,
    const void* __restrict__ Wv, const void* __restrict__ bv,
    short* __restrict__ Qt, short* __restrict__ Kt, short* __restrict__ Vt,
    const int* __restrict__ flags)
{
  __shared__ __align__(16) char smem[128 * 136 * 2];
  short* As = (short*)smem;
  short* Bs = As + 128 * PITCH;
  short* Ct = (short*)smem;
  const int isf32 = flags[0];
  const int t = threadIdx.x;
  const int lb = blockIdx.x;
  const int m0 = ((lb & 7) * 4 + ((lb >> 3) & 3)) * 128;
  const int n0 = (lb >> 5) * 128;
  const int which = blockIdx.y;
  const void* __restrict__ W = (which == 0) ? Wq : (which == 1) ? Wk : Wv;
  const void* __restrict__ bias = (which == 0) ? bq : (which == 1) ? bk : bv;
  const int lane = t & 63, wvi = t >> 6;
  const int wr = wvi >> 1, wc = wvi & 1;
  const int lm = lane & 15, lq = lane >> 4;
  f32x4 acc[4][4] = {};

  for (int k0 = 0; k0 < 1024; k0 += 32) {
    __syncthreads();
#pragma unroll
    for (int i = 0; i < 2; ++i) {
      int l = t + i * 256;
      int row = l >> 2, kk = (l & 3) << 3;
      *(short8*)&As[row * PITCH + kk] = ld8(x, (size_t)(m0 + row) * 1024 + k0 + kk, isf32);
      *(short8*)&Bs[row * PITCH + kk] = ld8(W, (size_t)(n0 + row) * 1024 + k0 + kk, isf32);
    }
    __syncthreads();
    short8 af[4], bf[4];
#pragma unroll
    for (int a = 0; a < 4; ++a) af[a] = *(const short8*)&As[(wr * 64 + a * 16 + lm) * PITCH + lq * 8];
#pragma unroll
    for (int b = 0; b < 4; ++b) bf[b] = *(const short8*)&Bs[(wc * 64 + b * 16 + lm) * PITCH + lq * 8];
#pragma unroll
    for (int a = 0; a < 4; ++a)
#pragma unroll
      for (int b = 0; b < 4; ++b)
        acc[a][b] = __builtin_amdgcn_mfma_f32_16x16x32_bf16(af[a], bf[b], acc[a][b], 0, 0, 0);
  }

  __syncthreads();
#pragma unroll
  for (int a = 0; a < 4; ++a)
#pragma unroll
    for (int b = 0; b < 4; ++b) {
      int col = wc * 64 + b * 16 + lm;
      float bv_ = ldf(bias, n0 + col, isf32);
#pragma unroll
      for (int r = 0; r < 4; ++r) {
        int row = wr * 64 + a * 16 + lq * 4 + r;
        Ct[row * 136 + col] = f2bf(acc[a][b][r] + bv_);
      }
    }
  __syncthreads();

  short* __restrict__ O = (which == 0) ? Qt : (which == 1) ? Kt : Vt;
#pragma unroll
  for (int j = 0; j < 8; ++j) {
    int id = t + j * 256;
    int d128 = id & 127, sg = (id >> 7) * 8;
    short vals[8];
#pragma unroll
    for (int i = 0; i < 8; ++i) vals[i] = Ct[(sg + i) * 136 + d128];
    int col = n0 + d128;
    int h = col >> 6, d = col & 63;
    int bb = m0 >> 10, sbase = (m0 & 1023) + sg;
    *(short8*)&O[(((size_t)(bb * 16 + h)) << 16) + ((size_t)d << 10) + sbase] = *(short8*)vals;
  }
}

// ------------------------------------------------- kA: column FFTs of Q and K
// ONE dispatch, all 64 planes: grid (32, 64), 128 threads (2 waves).
// Q side (bx 0..15): pair of d-columns per wave, scale 1/8 folded in,
//   Qhat[z*64+d][slot] in SCRAMBLED-u slot order (linear (l,r) write).
// K side (bx 16..31): one d-pair per wave packed complex, wave-private LDS
//   scatter to natural order, Hermitian split, Khat[z*64+d][v] natural.
__global__ __launch_bounds__(128) void kA_qkfft(
    const short* __restrict__ Qt, const short* __restrict__ Kt,
    __half2* __restrict__ Qhat, __half2* __restrict__ Khat)
{
  __shared__ float2 sbuf[2][1024];
  const int lane = threadIdx.x & 63, w = threadIdx.x >> 6;
  const int z = blockIdx.y;
  const int bx = blockIdx.x;
  if (bx < 16) {
    const short* qp = Qt + ((size_t)z << 16);
    const int d0 = bx * 4 + w * 2;
    float2 x[16], y[16];
#pragma unroll
    for (int j = 0; j < 16; ++j) {
      x[j] = make_float2(0.125f * bf2f(qp[(d0 << 10) + lane + 64 * j]), 0.f);
      y[j] = make_float2(0.125f * bf2f(qp[((d0 + 1) << 10) + lane + 64 * j]), 0.f);
    }
    wfft1024_dif2<-1>(x, y, lane);
    __half2* o0 = Qhat + (((size_t)(z * 64 + d0)) << 10);
    __half2* o1 = o0 + 1024;
#pragma unroll
    for (int r = 0; r < 16; ++r) {
      o0[lane + 64 * r] = __float22half2_rn(x[r]);
      o1[lane + 64 * r] = __float22half2_rn(y[r]);
    }
  } else {
    const short* kp = Kt + ((size_t)z << 16);
    const int p = (bx - 16) * 2 + w;
    const int d0 = 2 * p;
    float2 x[16];
#pragma unroll
    for (int j = 0; j < 16; ++j)
      x[j] = make_float2(bf2f(kp[(d0 << 10) + lane + 64 * j]),
                         bf2f(kp[((d0 + 1) << 10) + lane + 64 * j]));
    wfft1024_dif<-1>(x, lane);
    const int rho[16] = {0, 8, 4, 12, 2, 10, 6, 14, 1, 9, 5, 13, 3, 11, 7, 15};
    const int bl6 = ((lane & 1) << 5) | ((lane & 2) << 3) | ((lane & 4) << 1) |
                    ((lane & 8) >> 1) | ((lane & 16) >> 3) | ((lane & 32) >> 5);
    float2* buf = sbuf[w];
#pragma unroll
    for (int r = 0; r < 16; ++r) buf[rho[r] + 16 * bl6] = x[r];
    __half2* o0 = Khat + (size_t)(z * 64 + d0) * 520;
    __half2* o1 = o0 + 520;
#pragma unroll 1
    for (int jj = 0; jj < 9; ++jj) {
      int v = lane + 64 * jj;
      if (v <= 512) {
        float2 A = buf[v], B = buf[(1024 - v) & 1023];
        // K1 = (Z + conj(Z~))/2 ; K2 = (Z - conj(Z~))/(2i)
        o0[v] = __float22half2_rn(make_float2((A.x + B.x) * 0.5f, (A.y - B.y) * 0.5f));
        o1[v] = __float22half2_rn(make_float2((A.y + B.y) * 0.5f, (B.x - A.x) * 0.5f));
      }
    }
  }
}

// ------------------------------------------------- kB: F2D = Khat x Qhat^T + gain
// C[v][u-slot], M=64 (v), N=128 (u), K=64 (d). fp16 MFMA, f32 accum.
__global__ __launch_bounds__(256) void kB_specmm(
    const __half2* __restrict__ Qhat, const __half2* __restrict__ Khat,
    __half2* __restrict__ Ct, const int* __restrict__ flags, int bh0)
{
  __shared__ unsigned short Are[64][72], Aim[64][72], Bre[128][72], Bim[128][72];
  const int t = threadIdx.x;
  const int u0 = blockIdx.x * 128;
  const int v0 = blockIdx.y * 64;
  const int zl = blockIdx.z;
  const int z = bh0 + zl;
  const float alpha = ((const float*)flags)[1];
  const bool a1 = (alpha == 1.0f);
  {
    const int d = t >> 2;
    const ushort2* src = (const ushort2*)(Khat + (size_t)(z * 64 + d) * 520);
    int vb = (t & 3) * 16;
#pragma unroll
    for (int j = 0; j < 16; ++j) {
      int v = v0 + vb + j;
      if (v > 519) v = 519;
      ushort2 e = src[v];
      int row = vb + j;
      int dc = d ^ (((row >> 4) & 3) << 4);  // bank-spread swizzle
      Are[row][dc] = e.x;
      Aim[row][dc] = e.y;
    }
    const ushort2* srcb = (const ushort2*)(Qhat + (((size_t)(z * 64 + d)) << 10) + u0);
    int ub = (t & 3) * 32;
#pragma unroll
    for (int j = 0; j < 32; ++j) {
      ushort2 e = srcb[ub + j];
      int row = ub + j;
      int dc = d ^ (((row >> 5) & 3) << 4);
      Bre[row][dc] = e.x;
      Bim[row][dc] = e.y;
    }
  }
  __syncthreads();

  const int lane = t & 63, wc = t >> 6;
  const int lm = lane & 15, lq = lane >> 4;
  f32x4 cre[4][2] = {}, cim[4][2] = {};
#pragma unroll
  for (int ks = 0; ks < 2; ++ks) {
    half8 ar[4], ai[4], aiN[4], br[2], bi[2];
#pragma unroll
    for (int a = 0; a < 4; ++a) {
      int dc = (ks * 32 + lq * 8) ^ ((a & 3) << 4);
      ar[a] = *(const half8*)&Are[a * 16 + lm][dc];
      ai[a] = *(const half8*)&Aim[a * 16 + lm][dc];
      int4 tm = *(int4*)&ai[a];
      tm.x ^= 0x80008000; tm.y ^= 0x80008000; tm.z ^= 0x80008000; tm.w ^= 0x80008000;
      aiN[a] = *(half8*)&tm;
    }
#pragma unroll
    for (int n = 0; n < 2; ++n) {
      int dc = (ks * 32 + lq * 8) ^ ((wc & 3) << 4);
      br[n] = *(const half8*)&Bre[wc * 32 + n * 16 + lm][dc];
      bi[n] = *(const half8*)&Bim[wc * 32 + n * 16 + lm][dc];
    }
#pragma unroll
    for (int a = 0; a < 4; ++a)
#pragma unroll
      for (int n = 0; n < 2; ++n) {
        cre[a][n] = __builtin_amdgcn_mfma_f32_16x16x32_f16(ar[a], br[n], cre[a][n], 0, 0, 0);
        cre[a][n] = __builtin_amdgcn_mfma_f32_16x16x32_f16(aiN[a], bi[n], cre[a][n], 0, 0, 0);
        cim[a][n] = __builtin_amdgcn_mfma_f32_16x16x32_f16(ar[a], bi[n], cim[a][n], 0, 0, 0);
        cim[a][n] = __builtin_amdgcn_mfma_f32_16x16x32_f16(ai[a], br[n], cim[a][n], 0, 0, 0);
      }
  }

  __half2* outp = Ct + (size_t)zl * 513 * 1024 + u0 + wc * 32;
#pragma unroll
  for (int a = 0; a < 4; ++a)
#pragma unroll
    for (int r = 0; r < 4; ++r) {
      int v = v0 + a * 16 + lq * 4 + r;
      if (v < 513) {
#pragma unroll
        for (int n = 0; n < 2; ++n) {
          float re = cre[a][n][r], im = cim[a][n][r];
          float wf = gainw(re, im, alpha, a1);
          outp[(size_t)v * 1024 + n * 16 + lm] =
              __float22half2_rn(make_float2(re * wf, im * wf));
        }
      }
    }
}

// ------------------------------------------------- k4: inverse u-FFT (in place)
// Reads F~[v][u-slot] (scrambled-u), writes G[v][q] natural. Two rows/wave.
__global__ __launch_bounds__(256) void k4_invfft(__half2* __restrict__ Ct)
{
  const int lane = threadIdx.x & 63;
  const int w = threadIdx.x >> 6;
  const int gv0 = blockIdx.x * 8 + w * 2;
  if (gv0 > 512) return;
  const bool has1 = (gv0 + 1 <= 512);
  __half2* __restrict__ row0 = Ct + (size_t)blockIdx.y * 513 * 1024 + ((size_t)gv0 << 10);
  __half2* __restrict__ row1 = row0 + 1024;
  float2 x[16], y[16];
#pragma unroll
  for (int j = 0; j < 16; ++j) x[j] = __half22float2(row0[lane + 64 * j]);
  if (has1) {
#pragma unroll
    for (int j = 0; j < 16; ++j) y[j] = __half22float2(row1[lane + 64 * j]);
  } else {
#pragma unroll
    for (int j = 0; j < 16; ++j) y[j] = make_float2(0.f, 0.f);
  }
  wfft1024_inv2(x, y, lane);
#pragma unroll
  for (int j = 0; j < 16; ++j) row0[lane + 64 * j] = __float22half2_rn(x[j]);
  if (has1) {
#pragma unroll
    for (int j = 0; j < 16; ++j) row1[lane + 64 * j] = __float22half2_rn(y[j]);
  }
}

// ------------------------------------------------- k56: inverse row FFT + softmax + PV
// 512 threads / 8 waves, SINGLE round: wave w owns p-pair w (rows 2w, 2w+1).
// GP overlay: Gbuf rows (half2, pitch 2052B, from 448) all read BEFORE the
// barrier; P rows (bf16, pitch 2080B, from 0) written after => no hazard.
__global__ __launch_bounds__(512) void k56_softmax_av(
    const __half2* __restrict__ Ct, const short* __restrict__ Vt,
    short* __restrict__ ctx, int bh0)
{
  __shared__ __align__(16) char GP[33280];
  const int tid = threadIdx.x;
  const int q0 = blockIdx.x * 16, z = blockIdx.y;
  const int lane = tid & 63, w = tid >> 6;  // w = 0..7
  const int lm = lane & 15, lq = lane >> 4;
  const __half2* __restrict__ in = Ct + (size_t)z * 513 * 1024;
#define GROW(m) ((__half2*)(GP + 448 + (m) * 2052))
  for (int id = tid; id < 2052; id += 512) {
    int v = id >> 2, qq = (id & 3) * 4;
    int4 o = *(const int4*)&in[(size_t)v * 1024 + q0 + qq];
    __half2* op = (__half2*)&o;
#pragma unroll
    for (int i = 0; i < 4; ++i) GROW(qq + i)[v] = op[i];
  }
  short* P = (short*)GP;  // row m at m*1040 shorts
  const int bl6 = ((lane & 1) << 5) | ((lane & 2) << 3) | ((lane & 4) << 1) |
                  ((lane & 8) >> 1) | ((lane & 16) >> 3) | ((lane & 32) >> 5);
  __syncthreads();  // Gbuf ready

  const int p = w;
  const __half2* g1 = GROW(2 * p);
  const __half2* g2 = GROW(2 * p + 1);
  float2 x[16];
  // gather z[v] = G1[v] + i*G2[v], Hermitian mirror for v>512 (natural order)
#pragma unroll
  for (int j = 0; j < 16; ++j) {
    int v = lane + 64 * j;
    float2 a, b;
    if (v <= 512) {
      a = __half22float2(g1[v]);
      b = __half22float2(g2[v]);
    } else {
      int v2 = 1024 - v;
      float2 aa = __half22float2(g1[v2]), bb = __half22float2(g2[v2]);
      a = make_float2(aa.x, -aa.y);
      b = make_float2(bb.x, -bb.y);
    }
    x[j] = make_float2(a.x - b.y, a.y + b.x);
  }

  wfft1024_dif<1>(x, lane);  // sum_v z W^{+vk}: Re = row 2p, Im = row 2p+1

  // wave-local softmax
  float m1 = -3.4e38f, m2 = -3.4e38f;
#pragma unroll
  for (int j = 0; j < 16; ++j) { m1 = fmaxf(m1, x[j].x); m2 = fmaxf(m2, x[j].y); }
#pragma unroll
  for (int s = 32; s > 0; s >>= 1) {
    m1 = fmaxf(m1, __shfl_xor(m1, s, 64));
    m2 = fmaxf(m2, __shfl_xor(m2, s, 64));
  }
  float s1 = 0.f, s2 = 0.f;
#pragma unroll
  for (int j = 0; j < 16; ++j) {
    float e1 = __expf(x[j].x - m1), e2 = __expf(x[j].y - m2);
    x[j] = make_float2(e1, e2);
    s1 += e1; s2 += e2;
  }
#pragma unroll
  for (int s = 32; s > 0; s >>= 1) {
    s1 += __shfl_xor(s1, s, 64);
    s2 += __shfl_xor(s2, s, 64);
  }
  float inv1 = 1.0f / s1, inv2 = 1.0f / s2;

  __syncthreads();  // ALL G reads done before ANY P writes

  {
    const int rho[16] = {0, 8, 4, 12, 2, 10, 6, 14, 1, 9, 5, 13, 3, 11, 7, 15};
#pragma unroll
    for (int j = 0; j < 16; ++j) {
      int k = rho[j] + 16 * bl6;
      P[(2 * p) * 1040 + k]     = f2bf(x[j].x * inv1);
      P[(2 * p + 1) * 1040 + k] = f2bf(x[j].y * inv2);
    }
  }
  __syncthreads();  // P complete

  // PV: wave w covers k in [w*128, w*128+128)
  const short* __restrict__ Vp = Vt + ((size_t)(bh0 + z) << 16);
  f32x4 acc[4] = {};
#pragma unroll
  for (int ks = 0; ks < 4; ++ks) {
    int k0 = w * 128 + ks * 32;
    short8 a0 = *(const short8*)&P[lm * 1040 + k0 + lq * 8];
#pragma unroll
    for (int b = 0; b < 4; ++b) {
      short8 bv = *(const short8*)&Vp[(size_t)(b * 16 + lm) * 1024 + k0 + lq * 8];
      acc[b] = __builtin_amdgcn_mfma_f32_16x16x32_bf16(a0, bv, acc[b], 0, 0, 0);
    }
  }
  __syncthreads();  // all P reads done; reuse GP for reduction
  float* red = (float*)GP;  // [w=8][q=16][d=64] = 32 KB
#pragma unroll
  for (int b = 0; b < 4; ++b)
#pragma unroll
    for (int r = 0; r < 4; ++r)
      red[(w * 16 + lq * 4 + r) * 64 + b * 16 + lm] = acc[b][r];
  __syncthreads();
  if (tid < 256) {
    int q = tid >> 4, d0 = (tid & 15) * 4;
    float s0 = 0.f, s1_ = 0.f, s2_ = 0.f, s3 = 0.f;
#pragma unroll
    for (int ww = 0; ww < 8; ++ww) {
      const float* rr = &red[(ww * 16 + q) * 64 + d0];
      s0 += rr[0]; s1_ += rr[1]; s2_ += rr[2]; s3 += rr[3];
    }
    short o4[4] = {f2bf(s0), f2bf(s1_), f2bf(s2_), f2bf(s3)};
    *(int2*)&ctx[(((size_t)(bh0 + z)) << 16) + (size_t)(q0 + q) * 64 + d0] = *(int2*)o4;
  }
#undef GROW
}

// ------------------------------------------------- k7: out = ctx @ Wo^T + bo (XCD-swizzled)
__global__ __launch_bounds__(256) void k7_out(
    const short* __restrict__ ctx, const void* __restrict__ Wo,
    const void* __restrict__ bo, void* __restrict__ out,
    const int* __restrict__ flags)
{
  __shared__ __align__(16) char smem[128 * 136 * 2];
  short* As = (short*)smem;
  short* Bs = As + 128 * PITCH;
  short* Ct = (short*)smem;
  const int isf32 = flags[0];
  const int t = threadIdx.x;
  const int lb = blockIdx.x;
  const int m0 = ((lb & 7) * 4 + ((lb >> 3) & 3)) * 128;
  const int n0 = (lb >> 5) * 128;
  const int lane = t & 63, wvi = t >> 6;
  const int wr = wvi >> 1, wc = wvi & 1;
  const int lm = lane & 15, lq = lane >> 4;
  f32x4 acc[4][4] = {};

  for (int k0 = 0; k0 < 1024; k0 += 32) {
    __syncthreads();
#pragma unroll
    for (int i = 0; i < 2; ++i) {
      int l = t + i * 256;
      int row = l >> 2, kk = (l & 3) << 3;
      int n = m0 + row, e = k0 + kk;
      size_t aaddr = (((size_t)((n >> 10) * 16 + (e >> 6))) << 16) + (size_t)((n & 1023) << 6) + (e & 63);
      *(int4*)&As[row * PITCH + kk] = *(const int4*)&ctx[aaddr];
      *(short8*)&Bs[row * PITCH + kk] = ld8(Wo, (size_t)(n0 + row) * 1024 + e, isf32);
    }
    __syncthreads();
    short8 af[4], bf[4];
#pragma unroll
    for (int a = 0; a < 4; ++a) af[a] = *(const short8*)&As[(wr * 64 + a * 16 + lm) * PITCH + lq * 8];
#pragma unroll
    for (int b = 0; b < 4; ++b) bf[b] = *(const short8*)&Bs[(wc * 64 + b * 16 + lm) * PITCH + lq * 8];
#pragma unroll
    for (int a = 0; a < 4; ++a)
#pragma unroll
      for (int b = 0; b < 4; ++b)
        acc[a][b] = __builtin_amdgcn_mfma_f32_16x16x32_bf16(af[a], bf[b], acc[a][b], 0, 0, 0);
  }

  if (isf32) {
#pragma unroll
    for (int a = 0; a < 4; ++a)
#pragma unroll
      for (int b = 0; b < 4; ++b) {
        int col = n0 + wc * 64 + b * 16 + lm;
        float bo_ = ldf(bo, col, 1);
#pragma unroll
        for (int r = 0; r < 4; ++r) {
          int row = m0 + wr * 64 + a * 16 + lq * 4 + r;
          ((float*)out)[(size_t)row * 1024 + col] = acc[a][b][r] + bo_;
        }
      }
    return;
  }
  __syncthreads();
#pragma unroll
  for (int a = 0; a < 4; ++a)
#pragma unroll
    for (int b = 0; b < 4; ++b) {
      int col = wc * 64 + b * 16 + lm;
      float bo_ = ldf(bo, n0 + col, 0);
#pragma unroll
      for (int r = 0; r < 4; ++r) {
        int row = wr * 64 + a * 16 + lq * 4 + r;
        Ct[row * 136 + col] = f2bf(acc[a][b][r] + bo_);
      }
    }
  __syncthreads();
#pragma unroll
  for (int j = 0; j < 8; ++j) {
    int id = t + j * 256;
    int row = id >> 4, c16 = (id & 15) * 8;
    short8 v = *(const short8*)&Ct[row * 136 + c16];
    *(short8*)&((short*)out)[(size_t)(m0 + row) * 1024 + n0 + c16] = v;
  }
}

// ------------------------------------------------- launch
extern "C" void kernel_launch(void* const* d_in, const int* in_sizes, int n_in,
                              void* d_out, int out_size, void* d_ws, size_t ws_size,
                              hipStream_t stream)
{
  const void* x  = d_in[0];
  const void* Wq = d_in[1];
  const void* bq = d_in[2];
  const void* Wk = d_in[3];
  const void* bk = d_in[4];
  const void* Wv = d_in[5];
  const void* bv = d_in[6];
  const void* Wo = d_in[7];
  const void* bo = d_in[8];
  const void* alphap = d_in[9];
  char* ws = (char*)d_ws;

  // Overlay layout (~59.9 MiB):
  //   Qt [0,8M) and Kt [8M,16M) are DEAD after kA; per-chunk Ct (16.81M)
  //   overlays [0, 16.81M). Vt starts at 17M (clear of Ct).
  const size_t VT_OFF = (size_t)17u << 20;
  const size_t CX_OFF = (size_t)25u << 20;
  const size_t QH_OFF = (size_t)33u << 20;                       // 64*64*1024*4 = 16 MiB
  const size_t KH_OFF = QH_OFF + (size_t)64 * 64 * 1024 * 4;     // 64*64*520*4 = 8.125 MiB
  const size_t FL_OFF = KH_OFF + (size_t)64 * 64 * 520 * 4;

  short*   Qt   = (short*)(ws);
  short*   Kt   = (short*)(ws + ((size_t)8u << 20));
  short*   Vt   = (short*)(ws + VT_OFF);
  short*   ctx  = (short*)(ws + CX_OFF);
  __half2* Ct   = (__half2*)(ws);          // overlays Qt/Kt (dead after kA)
  __half2* Qhat = (__half2*)(ws + QH_OFF);
  __half2* Khat = (__half2*)(ws + KH_OFF);
  int*     flags = (int*)(ws + FL_OFF);

  k0_detect<<<1, 256, 0, stream>>>((const unsigned*)x, alphap, flags);
  k1_qkv<<<dim3(256, 3), 256, 0, stream>>>(x, Wq, bq, Wk, bk, Wv, bv, Qt, Kt, Vt, flags);
  kA_qkfft<<<dim3(32, 64), 128, 0, stream>>>(Qt, Kt, Qhat, Khat);
  for (int c = 0; c < 8; ++c) {
    int bh0 = c * 8;
    kB_specmm<<<dim3(8, 9, 8), 256, 0, stream>>>(Qhat, Khat, Ct, flags, bh0);
    k4_invfft<<<dim3(65, 8), 256, 0, stream>>>(Ct);
    k56_softmax_av<<<dim3(64, 8), 512, 0, stream>>>(Ct, Vt, ctx, bh0);
  }
  k7_out<<<256, 256, 0, stream>>>(ctx, Wo, bo, d_out, flags);
}

// Round 5
// 689.427 us; speedup vs baseline: 1.4460x; 1.1601x over previous
//
#include <hip/hip_runtime.h>
#include <hip/hip_fp16.h>

// SpectralAttention: B=4, S=1024, E=1024, H=16, HD=64.
// Identity: real(ifft2(F*exp(i*phi))) == ifft2(F * cos(phi)) for real scores
// => real spectral gain, Hermitian half-spectrum (v=0..512).
//
// Round-10:
//  - Dual-path launch: if ws_size >= ~169 MiB, run the mid-loop as ONE
//    dispatch per kernel over all 64 planes (28 dispatches -> 7); else the
//    proven 8-chunk path. Kernels are identical in both paths.
//  - k1: BK=64 (half the barriers, 32 MFMA/phase, two k-half fragment loads).
//
// Chunked layout (~59.9 MiB):  Qt 8M | Kt 8M (both overlaid by per-chunk Ct
//   16.81M) | Vt@17M | ctx@25M | Qhat@33M 16M | Khat 8.125M | flags
// Big layout (~168.4 MiB): Ct-all 128.25M (overlays Qt/Kt) | Vt | ctx |
//   Qhat | Khat | flags

typedef __attribute__((ext_vector_type(8))) short short8;
typedef __attribute__((ext_vector_type(8))) _Float16 half8;
typedef __attribute__((ext_vector_type(4))) float f32x4;

#define PITCH 40    // k7 staging pitch (BK=32)
#define PITCH1 72   // k1 staging pitch (BK=64)

__device__ __forceinline__ float bf2f(short v) {
  return __uint_as_float(((unsigned)(unsigned short)v) << 16);
}
__device__ __forceinline__ short f2bf(float f) {
  unsigned u = __float_as_uint(f);
  u += 0x7FFFu + ((u >> 16) & 1u);  // RNE
  return (short)(u >> 16);
}

__device__ __forceinline__ short8 ld8(const void* p, size_t idx, int isf32) {
  short8 r;
  if (isf32) {
    const float* f = (const float*)p + idx;
    float4 a = *(const float4*)f;
    float4 b = *(const float4*)(f + 4);
    r[0] = f2bf(a.x); r[1] = f2bf(a.y); r[2] = f2bf(a.z); r[3] = f2bf(a.w);
    r[4] = f2bf(b.x); r[5] = f2bf(b.y); r[6] = f2bf(b.z); r[7] = f2bf(b.w);
  } else {
    r = *(const short8*)((const short*)p + idx);
  }
  return r;
}
__device__ __forceinline__ float ldf(const void* p, int idx, int isf32) {
  return isf32 ? ((const float*)p)[idx] : bf2f(((const short*)p)[idx]);
}

__device__ __forceinline__ float2 cmul(float2 a, float2 b) {
  return make_float2(a.x * b.x - a.y * b.y, a.x * b.y + a.y * b.x);
}
__device__ __forceinline__ float2 cmulc(float2 a, float2 b) {  // a * conj(b)
  return make_float2(a.x * b.x + a.y * b.y, a.y * b.x - a.x * b.y);
}
__device__ __forceinline__ float2 cadd(float2 a, float2 b) {
  return make_float2(a.x + b.x, a.y + b.y);
}
__device__ __forceinline__ float2 csub(float2 a, float2 b) {
  return make_float2(a.x - b.x, a.y - b.y);
}

// ================== wave-register 1024-pt FFT (16 in-reg x 64 cross-lane) ==
// Layout: lane l holds z[l + 64*j], j=0..15 (n1 = lane, n2 = reg).
// Forward DIF output: (lane l, reg r) holds F[bitrev4(r) + 16*bitrev6(l)].
// wfft1024_dif<-1> = true DFT (W^-), <+1> = unnormalized inverse (W^+).
// wfft1024_inv2 = exact stage-mirror of dif<-1>; dif(-1) o inv = 1024*I.

template <int SGN>
__device__ __forceinline__ void dft16_dif(float2* x) {
  const float C16[8] = {1.f, 0.92387953f, 0.70710678f, 0.38268343f,
                        0.f, -0.38268343f, -0.70710678f, -0.92387953f};
  const float S16[8] = {0.f, 0.38268343f, 0.70710678f, 0.92387953f,
                        1.f, 0.92387953f, 0.70710678f, 0.38268343f};
#pragma unroll
  for (int h = 8; h >= 1; h >>= 1)
#pragma unroll
    for (int b = 0; b < 16; b += 2 * h)
#pragma unroll
      for (int i = 0; i < h; ++i) {
        const int e = i * (8 / h);
        float2 u = x[b + i], v = x[b + i + h];
        x[b + i] = cadd(u, v);
        float2 d = csub(u, v);
        float2 w = make_float2(C16[e], SGN > 0 ? S16[e] : -S16[e]);
        x[b + i + h] = (e == 0) ? d : cmul(d, w);
      }
}

__device__ __forceinline__ void dit16_inv(float2* x) {
  const float C16[8] = {1.f, 0.92387953f, 0.70710678f, 0.38268343f,
                        0.f, -0.38268343f, -0.70710678f, -0.92387953f};
  const float S16[8] = {0.f, 0.38268343f, 0.70710678f, 0.92387953f,
                        1.f, 0.92387953f, 0.70710678f, 0.38268343f};
#pragma unroll
  for (int h = 1; h <= 8; h <<= 1)
#pragma unroll
    for (int b = 0; b < 16; b += 2 * h)
#pragma unroll
      for (int i = 0; i < h; ++i) {
        const int e = i * (8 / h);
        float2 w = make_float2(C16[e], -S16[e]);
        float2 u = x[b + i];
        float2 vh = (e == 0) ? x[b + i + h] : cmulc(x[b + i + h], w);
        x[b + i] = cadd(u, vh);
        x[b + i + h] = csub(u, vh);
      }
}

template <int SGN>
__device__ __forceinline__ void midtw(float2* x, int lane) {
  const int rho[16] = {0, 8, 4, 12, 2, 10, 6, 14, 1, 9, 5, 13, 3, 11, 7, 15};
  float s, c;
  __sincosf((float)lane * 0.00613592315f, &s, &c);  // 2pi/1024
  float2 w = make_float2(c, SGN > 0 ? s : -s);
  float2 run = w;
  x[8] = cmul(x[8], run);
#pragma unroll
  for (int e = 2; e < 16; ++e) {
    run = cmul(run, w);
    x[rho[e]] = cmul(x[rho[e]], run);
  }
}

template <int SGN>
__device__ __forceinline__ void xlane_dif(float2* x, int lane) {
#pragma unroll
  for (int h = 32; h >= 1; h >>= 1) {
    const int e = (lane & (h - 1)) * (32 / h);
    float s, c;
    __sincosf((float)e * 0.09817477042f, &s, &c);  // 2pi/64
    float2 w = make_float2(c, SGN > 0 ? s : -s);
    const bool hi = (lane & h) != 0;
#pragma unroll
    for (int r = 0; r < 16; ++r) {
      float2 t = x[r];
      float2 p;
      p.x = __shfl_xor(t.x, h, 64);
      p.y = __shfl_xor(t.y, h, 64);
      x[r] = hi ? cmul(csub(p, t), w) : cadd(t, p);
    }
  }
}

template <int SGN>
__device__ __forceinline__ void wfft1024_dif(float2* x, int lane) {
  dft16_dif<SGN>(x);
  midtw<SGN>(x, lane);
  xlane_dif<SGN>(x, lane);
}

// -------- paired (two-row) variants: shared twiddles, 2x ILP per stage ----
template <int SGN>
__device__ __forceinline__ void midtw2(float2* x, float2* y, int lane) {
  const int rho[16] = {0, 8, 4, 12, 2, 10, 6, 14, 1, 9, 5, 13, 3, 11, 7, 15};
  float s, c;
  __sincosf((float)lane * 0.00613592315f, &s, &c);
  float2 w = make_float2(c, SGN > 0 ? s : -s);
  float2 run = w;
  x[8] = cmul(x[8], run);
  y[8] = cmul(y[8], run);
#pragma unroll
  for (int e = 2; e < 16; ++e) {
    run = cmul(run, w);
    x[rho[e]] = cmul(x[rho[e]], run);
    y[rho[e]] = cmul(y[rho[e]], run);
  }
}

__device__ __forceinline__ void midtw_inv2(float2* x, float2* y, int lane) {
  const int rho[16] = {0, 8, 4, 12, 2, 10, 6, 14, 1, 9, 5, 13, 3, 11, 7, 15};
  float s, c;
  __sincosf((float)lane * 0.00613592315f, &s, &c);
  float2 w = make_float2(c, -s);
  float2 run = w;
  x[8] = cmulc(x[8], run);
  y[8] = cmulc(y[8], run);
#pragma unroll
  for (int e = 2; e < 16; ++e) {
    run = cmul(run, w);
    x[rho[e]] = cmulc(x[rho[e]], run);
    y[rho[e]] = cmulc(y[rho[e]], run);
  }
}

template <int SGN>
__device__ __forceinline__ void xlane_dif2(float2* x, float2* y, int lane) {
#pragma unroll
  for (int h = 32; h >= 1; h >>= 1) {
    const int e = (lane & (h - 1)) * (32 / h);
    float s, c;
    __sincosf((float)e * 0.09817477042f, &s, &c);
    float2 w = make_float2(c, SGN > 0 ? s : -s);
    const bool hi = (lane & h) != 0;
#pragma unroll
    for (int r = 0; r < 16; ++r) {
      float2 t = x[r];
      float2 p;
      p.x = __shfl_xor(t.x, h, 64);
      p.y = __shfl_xor(t.y, h, 64);
      x[r] = hi ? cmul(csub(p, t), w) : cadd(t, p);
    }
#pragma unroll
    for (int r = 0; r < 16; ++r) {
      float2 t = y[r];
      float2 p;
      p.x = __shfl_xor(t.x, h, 64);
      p.y = __shfl_xor(t.y, h, 64);
      y[r] = hi ? cmul(csub(p, t), w) : cadd(t, p);
    }
  }
}

__device__ __forceinline__ void xlane_dit_inv2(float2* x, float2* y, int lane) {
#pragma unroll
  for (int h = 1; h <= 32; h <<= 1) {
    const int e = (lane & (h - 1)) * (32 / h);
    float s, c;
    __sincosf((float)e * 0.09817477042f, &s, &c);
    float2 w = make_float2(c, -s);
    const bool hi = (lane & h) != 0;
#pragma unroll
    for (int r = 0; r < 16; ++r) {
      float2 t = x[r];
      if (hi) t = cmulc(t, w);
      float2 p;
      p.x = __shfl_xor(t.x, h, 64);
      p.y = __shfl_xor(t.y, h, 64);
      x[r] = hi ? csub(p, t) : cadd(t, p);
    }
#pragma unroll
    for (int r = 0; r < 16; ++r) {
      float2 t = y[r];
      if (hi) t = cmulc(t, w);
      float2 p;
      p.x = __shfl_xor(t.x, h, 64);
      p.y = __shfl_xor(t.y, h, 64);
      y[r] = hi ? csub(p, t) : cadd(t, p);
    }
  }
}

template <int SGN>
__device__ __forceinline__ void wfft1024_dif2(float2* x, float2* y, int lane) {
  dft16_dif<SGN>(x);
  dft16_dif<SGN>(y);
  midtw2<SGN>(x, y, lane);
  xlane_dif2<SGN>(x, y, lane);
}
__device__ __forceinline__ void wfft1024_inv2(float2* x, float2* y, int lane) {
  xlane_dit_inv2(x, y, lane);
  midtw_inv2(x, y, lane);
  dit16_inv(x);
  dit16_inv(y);
}

// spectral gain; 1/N^2 folded in. alpha==1: cos(atan t) == rsqrt(1+t^2).
__device__ __forceinline__ float gainw(float re, float im, float alpha, bool a1) {
  float mag2 = re * re + im * im;
  float t = 0.5f * __logf(mag2 + 1e-20f);
  if (a1) return __builtin_amdgcn_rsqf(fmaf(t, t, 1.0f)) * (1.0f / 1048576.0f);
  return __cosf(alpha * atanf(t)) * (1.0f / 1048576.0f);
}

// ------------------------------------------------- k0: dtype detect + alpha
__global__ void k0_detect(const unsigned* __restrict__ q,
                          const void* __restrict__ alphap, int* __restrict__ flags) {
  __shared__ float smax[256];
  __shared__ int szero[256];
  int t = threadIdx.x;
  float mx = 0.f; int zc = 0;
  for (int i = t; i < 16384; i += 256) {
    unsigned w = q[i];
    unsigned lo = w & 0xFFFFu;
    float v = fabsf(__uint_as_float(lo << 16));
    if (!(v <= 1e30f)) v = 1e30f;
    mx = fmaxf(mx, v);
    zc += (lo == 0u);
  }
  smax[t] = mx; szero[t] = zc;
  __syncthreads();
  for (int s = 128; s > 0; s >>= 1) {
    if (t < s) { smax[t] = fmaxf(smax[t], smax[t + s]); szero[t] += szero[t + s]; }
    __syncthreads();
  }
  if (t == 0) {
    int isf32 = (smax[0] > 100.f) || (szero[0] > 12288);
    flags[0] = isf32;
    float alpha = isf32 ? *(const float*)alphap : bf2f(*(const short*)alphap);
    ((float*)flags)[1] = alpha;
  }
}

// ------------------------------------------------- k1: QKV projection (XCD-swizzled)
// BK=64 (half the barriers of BK=32). Outputs transposed: O[plane][d][s].
__global__ __launch_bounds__(256) void k1_qkv(
    const void* __restrict__ x,
    const void* __restrict__ Wq, const void* __restrict__ bq,
    const void* __restrict__ Wk, const void* __restrict__ bk,
    const void* __restrict__ Wv, const void* __restrict__ bv,
    short* __restrict__ Qt, short* __restrict__ Kt, short* __restrict__ Vt,
    const int* __restrict__ flags)
{
  __shared__ __align__(16) char smem[128 * PITCH1 * 2 * 2];  // 36864 B
  short* As = (short*)smem;
  short* Bs = As + 128 * PITCH1;
  short* Ct = (short*)smem;  // epilogue overlay (34816 B)
  const int isf32 = flags[0];
  const int t = threadIdx.x;
  const int lb = blockIdx.x;
  const int m0 = ((lb & 7) * 4 + ((lb >> 3) & 3)) * 128;
  const int n0 = (lb >> 5) * 128;
  const int which = blockIdx.y;
  const void* __restrict__ W = (which == 0) ? Wq : (which == 1) ? Wk : Wv;
  const void* __restrict__ bias = (which == 0) ? bq : (which == 1) ? bk : bv;
  const int lane = t & 63, wvi = t >> 6;
  const int wr = wvi >> 1, wc = wvi & 1;
  const int lm = lane & 15, lq = lane >> 4;
  f32x4 acc[4][4] = {};

  for (int k0 = 0; k0 < 1024; k0 += 64) {
    __syncthreads();
#pragma unroll
    for (int i = 0; i < 4; ++i) {
      int l = t + i * 256;
      int row = l >> 3, kk = (l & 7) << 3;
      *(short8*)&As[row * PITCH1 + kk] = ld8(x, (size_t)(m0 + row) * 1024 + k0 + kk, isf32);
      *(short8*)&Bs[row * PITCH1 + kk] = ld8(W, (size_t)(n0 + row) * 1024 + k0 + kk, isf32);
    }
    __syncthreads();
#pragma unroll
    for (int kh = 0; kh < 2; ++kh) {
      short8 af[4], bf[4];
#pragma unroll
      for (int a = 0; a < 4; ++a)
        af[a] = *(const short8*)&As[(wr * 64 + a * 16 + lm) * PITCH1 + kh * 32 + lq * 8];
#pragma unroll
      for (int b = 0; b < 4; ++b)
        bf[b] = *(const short8*)&Bs[(wc * 64 + b * 16 + lm) * PITCH1 + kh * 32 + lq * 8];
#pragma unroll
      for (int a = 0; a < 4; ++a)
#pragma unroll
        for (int b = 0; b < 4; ++b)
          acc[a][b] = __builtin_amdgcn_mfma_f32_16x16x32_bf16(af[a], bf[b], acc[a][b], 0, 0, 0);
    }
  }

  __syncthreads();
#pragma unroll
  for (int a = 0; a < 4; ++a)
#pragma unroll
    for (int b = 0; b < 4; ++b) {
      int col = wc * 64 + b * 16 + lm;
      float bv_ = ldf(bias, n0 + col, isf32);
#pragma unroll
      for (int r = 0; r < 4; ++r) {
        int row = wr * 64 + a * 16 + lq * 4 + r;
        Ct[row * 136 + col] = f2bf(acc[a][b][r] + bv_);
      }
    }
  __syncthreads();

  short* __restrict__ O = (which == 0) ? Qt : (which == 1) ? Kt : Vt;
#pragma unroll
  for (int j = 0; j < 8; ++j) {
    int id = t + j * 256;
    int d128 = id & 127, sg = (id >> 7) * 8;
    short vals[8];
#pragma unroll
    for (int i = 0; i < 8; ++i) vals[i] = Ct[(sg + i) * 136 + d128];
    int col = n0 + d128;
    int h = col >> 6, d = col & 63;
    int bb = m0 >> 10, sbase = (m0 & 1023) + sg;
    *(short8*)&O[(((size_t)(bb * 16 + h)) << 16) + ((size_t)d << 10) + sbase] = *(short8*)vals;
  }
}

// ------------------------------------------------- kA: column FFTs of Q and K
// ONE dispatch, all 64 planes: grid (32, 64), 128 threads (2 waves).
__global__ __launch_bounds__(128) void kA_qkfft(
    const short* __restrict__ Qt, const short* __restrict__ Kt,
    __half2* __restrict__ Qhat, __half2* __restrict__ Khat)
{
  __shared__ float2 sbuf[2][1024];
  const int lane = threadIdx.x & 63, w = threadIdx.x >> 6;
  const int z = blockIdx.y;
  const int bx = blockIdx.x;
  if (bx < 16) {
    const short* qp = Qt + ((size_t)z << 16);
    const int d0 = bx * 4 + w * 2;
    float2 x[16], y[16];
#pragma unroll
    for (int j = 0; j < 16; ++j) {
      x[j] = make_float2(0.125f * bf2f(qp[(d0 << 10) + lane + 64 * j]), 0.f);
      y[j] = make_float2(0.125f * bf2f(qp[((d0 + 1) << 10) + lane + 64 * j]), 0.f);
    }
    wfft1024_dif2<-1>(x, y, lane);
    __half2* o0 = Qhat + (((size_t)(z * 64 + d0)) << 10);
    __half2* o1 = o0 + 1024;
#pragma unroll
    for (int r = 0; r < 16; ++r) {
      o0[lane + 64 * r] = __float22half2_rn(x[r]);
      o1[lane + 64 * r] = __float22half2_rn(y[r]);
    }
  } else {
    const short* kp = Kt + ((size_t)z << 16);
    const int p = (bx - 16) * 2 + w;
    const int d0 = 2 * p;
    float2 x[16];
#pragma unroll
    for (int j = 0; j < 16; ++j)
      x[j] = make_float2(bf2f(kp[(d0 << 10) + lane + 64 * j]),
                         bf2f(kp[((d0 + 1) << 10) + lane + 64 * j]));
    wfft1024_dif<-1>(x, lane);
    const int rho[16] = {0, 8, 4, 12, 2, 10, 6, 14, 1, 9, 5, 13, 3, 11, 7, 15};
    const int bl6 = ((lane & 1) << 5) | ((lane & 2) << 3) | ((lane & 4) << 1) |
                    ((lane & 8) >> 1) | ((lane & 16) >> 3) | ((lane & 32) >> 5);
    float2* buf = sbuf[w];
#pragma unroll
    for (int r = 0; r < 16; ++r) buf[rho[r] + 16 * bl6] = x[r];
    __half2* o0 = Khat + (size_t)(z * 64 + d0) * 520;
    __half2* o1 = o0 + 520;
#pragma unroll 1
    for (int jj = 0; jj < 9; ++jj) {
      int v = lane + 64 * jj;
      if (v <= 512) {
        float2 A = buf[v], B = buf[(1024 - v) & 1023];
        // K1 = (Z + conj(Z~))/2 ; K2 = (Z - conj(Z~))/(2i)
        o0[v] = __float22half2_rn(make_float2((A.x + B.x) * 0.5f, (A.y - B.y) * 0.5f));
        o1[v] = __float22half2_rn(make_float2((A.y + B.y) * 0.5f, (B.x - A.x) * 0.5f));
      }
    }
  }
}

// ------------------------------------------------- kB: F2D = Khat x Qhat^T + gain
// C[v][u-slot], M=64 (v), N=128 (u), K=64 (d). fp16 MFMA, f32 accum.
// Ct plane index = blockIdx.z; Qhat/Khat plane = bh0 + blockIdx.z.
__global__ __launch_bounds__(256) void kB_specmm(
    const __half2* __restrict__ Qhat, const __half2* __restrict__ Khat,
    __half2* __restrict__ Ct, const int* __restrict__ flags, int bh0)
{
  __shared__ unsigned short Are[64][72], Aim[64][72], Bre[128][72], Bim[128][72];
  const int t = threadIdx.x;
  const int u0 = blockIdx.x * 128;
  const int v0 = blockIdx.y * 64;
  const int zl = blockIdx.z;
  const int z = bh0 + zl;
  const float alpha = ((const float*)flags)[1];
  const bool a1 = (alpha == 1.0f);
  {
    const int d = t >> 2;
    const ushort2* src = (const ushort2*)(Khat + (size_t)(z * 64 + d) * 520);
    int vb = (t & 3) * 16;
#pragma unroll
    for (int j = 0; j < 16; ++j) {
      int v = v0 + vb + j;
      if (v > 519) v = 519;
      ushort2 e = src[v];
      int row = vb + j;
      int dc = d ^ (((row >> 4) & 3) << 4);  // bank-spread swizzle
      Are[row][dc] = e.x;
      Aim[row][dc] = e.y;
    }
    const ushort2* srcb = (const ushort2*)(Qhat + (((size_t)(z * 64 + d)) << 10) + u0);
    int ub = (t & 3) * 32;
#pragma unroll
    for (int j = 0; j < 32; ++j) {
      ushort2 e = srcb[ub + j];
      int row = ub + j;
      int dc = d ^ (((row >> 5) & 3) << 4);
      Bre[row][dc] = e.x;
      Bim[row][dc] = e.y;
    }
  }
  __syncthreads();

  const int lane = t & 63, wc = t >> 6;
  const int lm = lane & 15, lq = lane >> 4;
  f32x4 cre[4][2] = {}, cim[4][2] = {};
#pragma unroll
  for (int ks = 0; ks < 2; ++ks) {
    half8 ar[4], ai[4], aiN[4], br[2], bi[2];
#pragma unroll
    for (int a = 0; a < 4; ++a) {
      int dc = (ks * 32 + lq * 8) ^ ((a & 3) << 4);
      ar[a] = *(const half8*)&Are[a * 16 + lm][dc];
      ai[a] = *(const half8*)&Aim[a * 16 + lm][dc];
      int4 tm = *(int4*)&ai[a];
      tm.x ^= 0x80008000; tm.y ^= 0x80008000; tm.z ^= 0x80008000; tm.w ^= 0x80008000;
      aiN[a] = *(half8*)&tm;
    }
#pragma unroll
    for (int n = 0; n < 2; ++n) {
      int dc = (ks * 32 + lq * 8) ^ ((wc & 3) << 4);
      br[n] = *(const half8*)&Bre[wc * 32 + n * 16 + lm][dc];
      bi[n] = *(const half8*)&Bim[wc * 32 + n * 16 + lm][dc];
    }
#pragma unroll
    for (int a = 0; a < 4; ++a)
#pragma unroll
      for (int n = 0; n < 2; ++n) {
        cre[a][n] = __builtin_amdgcn_mfma_f32_16x16x32_f16(ar[a], br[n], cre[a][n], 0, 0, 0);
        cre[a][n] = __builtin_amdgcn_mfma_f32_16x16x32_f16(aiN[a], bi[n], cre[a][n], 0, 0, 0);
        cim[a][n] = __builtin_amdgcn_mfma_f32_16x16x32_f16(ar[a], bi[n], cim[a][n], 0, 0, 0);
        cim[a][n] = __builtin_amdgcn_mfma_f32_16x16x32_f16(ai[a], br[n], cim[a][n], 0, 0, 0);
      }
  }

  __half2* outp = Ct + (size_t)zl * 513 * 1024 + u0 + wc * 32;
#pragma unroll
  for (int a = 0; a < 4; ++a)
#pragma unroll
    for (int r = 0; r < 4; ++r) {
      int v = v0 + a * 16 + lq * 4 + r;
      if (v < 513) {
#pragma unroll
        for (int n = 0; n < 2; ++n) {
          float re = cre[a][n][r], im = cim[a][n][r];
          float wf = gainw(re, im, alpha, a1);
          outp[(size_t)v * 1024 + n * 16 + lm] =
              __float22half2_rn(make_float2(re * wf, im * wf));
        }
      }
    }
}

// ------------------------------------------------- k4: inverse u-FFT (in place)
// Reads F~[v][u-slot] (scrambled-u), writes G[v][q] natural. Two rows/wave.
__global__ __launch_bounds__(256) void k4_invfft(__half2* __restrict__ Ct)
{
  const int lane = threadIdx.x & 63;
  const int w = threadIdx.x >> 6;
  const int gv0 = blockIdx.x * 8 + w * 2;
  if (gv0 > 512) return;
  const bool has1 = (gv0 + 1 <= 512);
  __half2* __restrict__ row0 = Ct + (size_t)blockIdx.y * 513 * 1024 + ((size_t)gv0 << 10);
  __half2* __restrict__ row1 = row0 + 1024;
  float2 x[16], y[16];
#pragma unroll
  for (int j = 0; j < 16; ++j) x[j] = __half22float2(row0[lane + 64 * j]);
  if (has1) {
#pragma unroll
    for (int j = 0; j < 16; ++j) y[j] = __half22float2(row1[lane + 64 * j]);
  } else {
#pragma unroll
    for (int j = 0; j < 16; ++j) y[j] = make_float2(0.f, 0.f);
  }
  wfft1024_inv2(x, y, lane);
#pragma unroll
  for (int j = 0; j < 16; ++j) row0[lane + 64 * j] = __float22half2_rn(x[j]);
  if (has1) {
#pragma unroll
    for (int j = 0; j < 16; ++j) row1[lane + 64 * j] = __float22half2_rn(y[j]);
  }
}

// ------------------------------------------------- k56: inverse row FFT + softmax + PV
// 512 threads / 8 waves, single round: wave w owns p-pair w (rows 2w, 2w+1).
// Ct plane = blockIdx.y; V plane = bh0 + blockIdx.y.
__global__ __launch_bounds__(512) void k56_softmax_av(
    const __half2* __restrict__ Ct, const short* __restrict__ Vt,
    short* __restrict__ ctx, int bh0)
{
  __shared__ __align__(16) char GP[33280];
  const int tid = threadIdx.x;
  const int q0 = blockIdx.x * 16, z = blockIdx.y;
  const int lane = tid & 63, w = tid >> 6;  // w = 0..7
  const int lm = lane & 15, lq = lane >> 4;
  const __half2* __restrict__ in = Ct + (size_t)z * 513 * 1024;
#define GROW(m) ((__half2*)(GP + 448 + (m) * 2052))
  for (int id = tid; id < 2052; id += 512) {
    int v = id >> 2, qq = (id & 3) * 4;
    int4 o = *(const int4*)&in[(size_t)v * 1024 + q0 + qq];
    __half2* op = (__half2*)&o;
#pragma unroll
    for (int i = 0; i < 4; ++i) GROW(qq + i)[v] = op[i];
  }
  short* P = (short*)GP;  // row m at m*1040 shorts
  const int bl6 = ((lane & 1) << 5) | ((lane & 2) << 3) | ((lane & 4) << 1) |
                  ((lane & 8) >> 1) | ((lane & 16) >> 3) | ((lane & 32) >> 5);
  __syncthreads();  // Gbuf ready

  const int p = w;
  const __half2* g1 = GROW(2 * p);
  const __half2* g2 = GROW(2 * p + 1);
  float2 x[16];
#pragma unroll
  for (int j = 0; j < 16; ++j) {
    int v = lane + 64 * j;
    float2 a, b;
    if (v <= 512) {
      a = __half22float2(g1[v]);
      b = __half22float2(g2[v]);
    } else {
      int v2 = 1024 - v;
      float2 aa = __half22float2(g1[v2]), bb = __half22float2(g2[v2]);
      a = make_float2(aa.x, -aa.y);
      b = make_float2(bb.x, -bb.y);
    }
    x[j] = make_float2(a.x - b.y, a.y + b.x);
  }

  wfft1024_dif<1>(x, lane);  // sum_v z W^{+vk}: Re = row 2p, Im = row 2p+1

  float m1 = -3.4e38f, m2 = -3.4e38f;
#pragma unroll
  for (int j = 0; j < 16; ++j) { m1 = fmaxf(m1, x[j].x); m2 = fmaxf(m2, x[j].y); }
#pragma unroll
  for (int s = 32; s > 0; s >>= 1) {
    m1 = fmaxf(m1, __shfl_xor(m1, s, 64));
    m2 = fmaxf(m2, __shfl_xor(m2, s, 64));
  }
  float s1 = 0.f, s2 = 0.f;
#pragma unroll
  for (int j = 0; j < 16; ++j) {
    float e1 = __expf(x[j].x - m1), e2 = __expf(x[j].y - m2);
    x[j] = make_float2(e1, e2);
    s1 += e1; s2 += e2;
  }
#pragma unroll
  for (int s = 32; s > 0; s >>= 1) {
    s1 += __shfl_xor(s1, s, 64);
    s2 += __shfl_xor(s2, s, 64);
  }
  float inv1 = 1.0f / s1, inv2 = 1.0f / s2;

  __syncthreads();  // ALL G reads done before ANY P writes

  {
    const int rho[16] = {0, 8, 4, 12, 2, 10, 6, 14, 1, 9, 5, 13, 3, 11, 7, 15};
#pragma unroll
    for (int j = 0; j < 16; ++j) {
      int k = rho[j] + 16 * bl6;
      P[(2 * p) * 1040 + k]     = f2bf(x[j].x * inv1);
      P[(2 * p + 1) * 1040 + k] = f2bf(x[j].y * inv2);
    }
  }
  __syncthreads();  // P complete

  // PV: wave w covers k in [w*128, w*128+128)
  const short* __restrict__ Vp = Vt + ((size_t)(bh0 + z) << 16);
  f32x4 acc[4] = {};
#pragma unroll
  for (int ks = 0; ks < 4; ++ks) {
    int k0 = w * 128 + ks * 32;
    short8 a0 = *(const short8*)&P[lm * 1040 + k0 + lq * 8];
#pragma unroll
    for (int b = 0; b < 4; ++b) {
      short8 bv = *(const short8*)&Vp[(size_t)(b * 16 + lm) * 1024 + k0 + lq * 8];
      acc[b] = __builtin_amdgcn_mfma_f32_16x16x32_bf16(a0, bv, acc[b], 0, 0, 0);
    }
  }
  __syncthreads();  // all P reads done; reuse GP for reduction
  float* red = (float*)GP;  // [w=8][q=16][d=64] = 32 KB
#pragma unroll
  for (int b = 0; b < 4; ++b)
#pragma unroll
    for (int r = 0; r < 4; ++r)
      red[(w * 16 + lq * 4 + r) * 64 + b * 16 + lm] = acc[b][r];
  __syncthreads();
  if (tid < 256) {
    int q = tid >> 4, d0 = (tid & 15) * 4;
    float s0 = 0.f, s1_ = 0.f, s2_ = 0.f, s3 = 0.f;
#pragma unroll
    for (int ww = 0; ww < 8; ++ww) {
      const float* rr = &red[(ww * 16 + q) * 64 + d0];
      s0 += rr[0]; s1_ += rr[1]; s2_ += rr[2]; s3 += rr[3];
    }
    short o4[4] = {f2bf(s0), f2bf(s1_), f2bf(s2_), f2bf(s3)};
    *(int2*)&ctx[(((size_t)(bh0 + z)) << 16) + (size_t)(q0 + q) * 64 + d0] = *(int2*)o4;
  }
#undef GROW
}

// ------------------------------------------------- k7: out = ctx @ Wo^T + bo (XCD-swizzled)
__global__ __launch_bounds__(256) void k7_out(
    const short* __restrict__ ctx, const void* __restrict__ Wo,
    const void* __restrict__ bo, void* __restrict__ out,
    const int* __restrict__ flags)
{
  __shared__ __align__(16) char smem[128 * 136 * 2];
  short* As = (short*)smem;
  short* Bs = As + 128 * PITCH;
  short* Ct = (short*)smem;
  const int isf32 = flags[0];
  const int t = threadIdx.x;
  const int lb = blockIdx.x;
  const int m0 = ((lb & 7) * 4 + ((lb >> 3) & 3)) * 128;
  const int n0 = (lb >> 5) * 128;
  const int lane = t & 63, wvi = t >> 6;
  const int wr = wvi >> 1, wc = wvi & 1;
  const int lm = lane & 15, lq = lane >> 4;
  f32x4 acc[4][4] = {};

  for (int k0 = 0; k0 < 1024; k0 += 32) {
    __syncthreads();
#pragma unroll
    for (int i = 0; i < 2; ++i) {
      int l = t + i * 256;
      int row = l >> 2, kk = (l & 3) << 3;
      int n = m0 + row, e = k0 + kk;
      size_t aaddr = (((size_t)((n >> 10) * 16 + (e >> 6))) << 16) + (size_t)((n & 1023) << 6) + (e & 63);
      *(int4*)&As[row * PITCH + kk] = *(const int4*)&ctx[aaddr];
      *(short8*)&Bs[row * PITCH + kk] = ld8(Wo, (size_t)(n0 + row) * 1024 + e, isf32);
    }
    __syncthreads();
    short8 af[4], bf[4];
#pragma unroll
    for (int a = 0; a < 4; ++a) af[a] = *(const short8*)&As[(wr * 64 + a * 16 + lm) * PITCH + lq * 8];
#pragma unroll
    for (int b = 0; b < 4; ++b) bf[b] = *(const short8*)&Bs[(wc * 64 + b * 16 + lm) * PITCH + lq * 8];
#pragma unroll
    for (int a = 0; a < 4; ++a)
#pragma unroll
      for (int b = 0; b < 4; ++b)
        acc[a][b] = __builtin_amdgcn_mfma_f32_16x16x32_bf16(af[a], bf[b], acc[a][b], 0, 0, 0);
  }

  if (isf32) {
#pragma unroll
    for (int a = 0; a < 4; ++a)
#pragma unroll
      for (int b = 0; b < 4; ++b) {
        int col = n0 + wc * 64 + b * 16 + lm;
        float bo_ = ldf(bo, col, 1);
#pragma unroll
        for (int r = 0; r < 4; ++r) {
          int row = m0 + wr * 64 + a * 16 + lq * 4 + r;
          ((float*)out)[(size_t)row * 1024 + col] = acc[a][b][r] + bo_;
        }
      }
    return;
  }
  __syncthreads();
#pragma unroll
  for (int a = 0; a < 4; ++a)
#pragma unroll
    for (int b = 0; b < 4; ++b) {
      int col = wc * 64 + b * 16 + lm;
      float bo_ = ldf(bo, n0 + col, 0);
#pragma unroll
      for (int r = 0; r < 4; ++r) {
        int row = wr * 64 + a * 16 + lq * 4 + r;
        Ct[row * 136 + col] = f2bf(acc[a][b][r] + bo_);
      }
    }
  __syncthreads();
#pragma unroll
  for (int j = 0; j < 8; ++j) {
    int id = t + j * 256;
    int row = id >> 4, c16 = (id & 15) * 8;
    short8 v = *(const short8*)&Ct[row * 136 + c16];
    *(short8*)&((short*)out)[(size_t)(m0 + row) * 1024 + n0 + c16] = v;
  }
}

// ------------------------------------------------- launch
extern "C" void kernel_launch(void* const* d_in, const int* in_sizes, int n_in,
                              void* d_out, int out_size, void* d_ws, size_t ws_size,
                              hipStream_t stream)
{
  const void* x  = d_in[0];
  const void* Wq = d_in[1];
  const void* bq = d_in[2];
  const void* Wk = d_in[3];
  const void* bk = d_in[4];
  const void* Wv = d_in[5];
  const void* bv = d_in[6];
  const void* Wo = d_in[7];
  const void* bo = d_in[8];
  const void* alphap = d_in[9];
  char* ws = (char*)d_ws;

  const size_t PLANE_CT = (size_t)513 * 1024 * 4;  // 2,101,248 B
  const size_t QH_SZ = (size_t)64 * 64 * 1024 * 4; // 16 MiB
  const size_t KH_SZ = (size_t)64 * 64 * 520 * 4;  // 8.125 MiB

  // ---- big path layout: Ct-all overlays Qt/Kt ----
  const size_t B_CT  = 0;
  const size_t B_VT  = 64 * PLANE_CT;            // 134,479,872
  const size_t B_CX  = B_VT + ((size_t)8u << 20);
  const size_t B_QH  = B_CX + ((size_t)8u << 20);
  const size_t B_KH  = B_QH + QH_SZ;
  const size_t B_FL  = B_KH + KH_SZ;
  const size_t B_NEED = B_FL + 256;

  if (ws_size >= B_NEED) {
    short*   Qt   = (short*)(ws);
    short*   Kt   = (short*)(ws + ((size_t)8u << 20));
    short*   Vt   = (short*)(ws + B_VT);
    short*   ctx  = (short*)(ws + B_CX);
    __half2* Ct   = (__half2*)(ws + B_CT);   // overlays Qt/Kt (dead after kA)
    __half2* Qhat = (__half2*)(ws + B_QH);
    __half2* Khat = (__half2*)(ws + B_KH);
    int*     flags = (int*)(ws + B_FL);

    k0_detect<<<1, 256, 0, stream>>>((const unsigned*)x, alphap, flags);
    k1_qkv<<<dim3(256, 3), 256, 0, stream>>>(x, Wq, bq, Wk, bk, Wv, bv, Qt, Kt, Vt, flags);
    kA_qkfft<<<dim3(32, 64), 128, 0, stream>>>(Qt, Kt, Qhat, Khat);
    kB_specmm<<<dim3(8, 9, 64), 256, 0, stream>>>(Qhat, Khat, Ct, flags, 0);
    k4_invfft<<<dim3(65, 64), 256, 0, stream>>>(Ct);
    k56_softmax_av<<<dim3(64, 64), 512, 0, stream>>>(Ct, Vt, ctx, 0);
    k7_out<<<256, 256, 0, stream>>>(ctx, Wo, bo, d_out, flags);
    return;
  }

  // ---- chunked fallback (proven ~59.9 MiB layout) ----
  const size_t VT_OFF = (size_t)17u << 20;
  const size_t CX_OFF = (size_t)25u << 20;
  const size_t QH_OFF = (size_t)33u << 20;
  const size_t KH_OFF = QH_OFF + QH_SZ;
  const size_t FL_OFF = KH_OFF + KH_SZ;

  short*   Qt   = (short*)(ws);
  short*   Kt   = (short*)(ws + ((size_t)8u << 20));
  short*   Vt   = (short*)(ws + VT_OFF);
  short*   ctx  = (short*)(ws + CX_OFF);
  __half2* Ct   = (__half2*)(ws);          // overlays Qt/Kt (dead after kA)
  __half2* Qhat = (__half2*)(ws + QH_OFF);
  __half2* Khat = (__half2*)(ws + KH_OFF);
  int*     flags = (int*)(ws + FL_OFF);

  k0_detect<<<1, 256, 0, stream>>>((const unsigned*)x, alphap, flags);
  k1_qkv<<<dim3(256, 3), 256, 0, stream>>>(x, Wq, bq, Wk, bk, Wv, bv, Qt, Kt, Vt, flags);
  kA_qkfft<<<dim3(32, 64), 128, 0, stream>>>(Qt, Kt, Qhat, Khat);
  for (int c = 0; c < 8; ++c) {
    int bh0 = c * 8;
    kB_specmm<<<dim3(8, 9, 8), 256, 0, stream>>>(Qhat, Khat, Ct, flags, bh0);
    k4_invfft<<<dim3(65, 8), 256, 0, stream>>>(Ct);
    k56_softmax_av<<<dim3(64, 8), 512, 0, stream>>>(Ct, Vt, ctx, bh0);
  }
  k7_out<<<256, 256, 0, stream>>>(ctx, Wo, bo, d_out, flags);
}

// Round 6
// 678.760 us; speedup vs baseline: 1.4687x; 1.0157x over previous
//
#include <hip/hip_runtime.h>
#include <hip/hip_fp16.h>

// SpectralAttention: B=4, S=1024, E=1024, H=16, HD=64.
// Identity: real(ifft2(F*exp(i*phi))) == ifft2(F * cos(phi)) for real scores
// => real spectral gain, Hermitian half-spectrum (v=0..512).
//
// Round-11 (k56 bank-conflict surgery; all else identical to round-10):
//  - P scatter: rho is an involution; a lane's 16 outputs tile the contiguous
//    16-short block at 16*bl6 -> in-register reorder + 2x ds_write_b128/row
//    (was 32 scalar b16 writes/wave at 16-way conflict).
//  - Gbuf pitch 2052 -> 2064 B (516 words = 4 mod 32): staging writes become
//    uniform 2-way (free). Single-barrier structure => no overlay hazard.
//
// Chunked layout (~59.9 MiB):  Qt 8M | Kt 8M (both overlaid by per-chunk Ct
//   16.81M) | Vt@17M | ctx@25M | Qhat@33M 16M | Khat 8.125M | flags
// Big layout (~168.4 MiB): Ct-all 128.25M (overlays Qt/Kt) | Vt | ctx |
//   Qhat | Khat | flags

typedef __attribute__((ext_vector_type(8))) short short8;
typedef __attribute__((ext_vector_type(8))) _Float16 half8;
typedef __attribute__((ext_vector_type(4))) float f32x4;

#define PITCH 40    // k7 staging pitch (BK=32)
#define PITCH1 72   // k1 staging pitch (BK=64)

__device__ __forceinline__ float bf2f(short v) {
  return __uint_as_float(((unsigned)(unsigned short)v) << 16);
}
__device__ __forceinline__ short f2bf(float f) {
  unsigned u = __float_as_uint(f);
  u += 0x7FFFu + ((u >> 16) & 1u);  // RNE
  return (short)(u >> 16);
}

__device__ __forceinline__ short8 ld8(const void* p, size_t idx, int isf32) {
  short8 r;
  if (isf32) {
    const float* f = (const float*)p + idx;
    float4 a = *(const float4*)f;
    float4 b = *(const float4*)(f + 4);
    r[0] = f2bf(a.x); r[1] = f2bf(a.y); r[2] = f2bf(a.z); r[3] = f2bf(a.w);
    r[4] = f2bf(b.x); r[5] = f2bf(b.y); r[6] = f2bf(b.z); r[7] = f2bf(b.w);
  } else {
    r = *(const short8*)((const short*)p + idx);
  }
  return r;
}
__device__ __forceinline__ float ldf(const void* p, int idx, int isf32) {
  return isf32 ? ((const float*)p)[idx] : bf2f(((const short*)p)[idx]);
}

__device__ __forceinline__ float2 cmul(float2 a, float2 b) {
  return make_float2(a.x * b.x - a.y * b.y, a.x * b.y + a.y * b.x);
}
__device__ __forceinline__ float2 cmulc(float2 a, float2 b) {  // a * conj(b)
  return make_float2(a.x * b.x + a.y * b.y, a.y * b.x - a.x * b.y);
}
__device__ __forceinline__ float2 cadd(float2 a, float2 b) {
  return make_float2(a.x + b.x, a.y + b.y);
}
__device__ __forceinline__ float2 csub(float2 a, float2 b) {
  return make_float2(a.x - b.x, a.y - b.y);
}

// ================== wave-register 1024-pt FFT (16 in-reg x 64 cross-lane) ==
// Layout: lane l holds z[l + 64*j], j=0..15 (n1 = lane, n2 = reg).
// Forward DIF output: (lane l, reg r) holds F[bitrev4(r) + 16*bitrev6(l)].
// wfft1024_dif<-1> = true DFT (W^-), <+1> = unnormalized inverse (W^+).
// wfft1024_inv2 = exact stage-mirror of dif<-1>; dif(-1) o inv = 1024*I.

template <int SGN>
__device__ __forceinline__ void dft16_dif(float2* x) {
  const float C16[8] = {1.f, 0.92387953f, 0.70710678f, 0.38268343f,
                        0.f, -0.38268343f, -0.70710678f, -0.92387953f};
  const float S16[8] = {0.f, 0.38268343f, 0.70710678f, 0.92387953f,
                        1.f, 0.92387953f, 0.70710678f, 0.38268343f};
#pragma unroll
  for (int h = 8; h >= 1; h >>= 1)
#pragma unroll
    for (int b = 0; b < 16; b += 2 * h)
#pragma unroll
      for (int i = 0; i < h; ++i) {
        const int e = i * (8 / h);
        float2 u = x[b + i], v = x[b + i + h];
        x[b + i] = cadd(u, v);
        float2 d = csub(u, v);
        float2 w = make_float2(C16[e], SGN > 0 ? S16[e] : -S16[e]);
        x[b + i + h] = (e == 0) ? d : cmul(d, w);
      }
}

__device__ __forceinline__ void dit16_inv(float2* x) {
  const float C16[8] = {1.f, 0.92387953f, 0.70710678f, 0.38268343f,
                        0.f, -0.38268343f, -0.70710678f, -0.92387953f};
  const float S16[8] = {0.f, 0.38268343f, 0.70710678f, 0.92387953f,
                        1.f, 0.92387953f, 0.70710678f, 0.38268343f};
#pragma unroll
  for (int h = 1; h <= 8; h <<= 1)
#pragma unroll
    for (int b = 0; b < 16; b += 2 * h)
#pragma unroll
      for (int i = 0; i < h; ++i) {
        const int e = i * (8 / h);
        float2 w = make_float2(C16[e], -S16[e]);
        float2 u = x[b + i];
        float2 vh = (e == 0) ? x[b + i + h] : cmulc(x[b + i + h], w);
        x[b + i] = cadd(u, vh);
        x[b + i + h] = csub(u, vh);
      }
}

template <int SGN>
__device__ __forceinline__ void midtw(float2* x, int lane) {
  const int rho[16] = {0, 8, 4, 12, 2, 10, 6, 14, 1, 9, 5, 13, 3, 11, 7, 15};
  float s, c;
  __sincosf((float)lane * 0.00613592315f, &s, &c);  // 2pi/1024
  float2 w = make_float2(c, SGN > 0 ? s : -s);
  float2 run = w;
  x[8] = cmul(x[8], run);
#pragma unroll
  for (int e = 2; e < 16; ++e) {
    run = cmul(run, w);
    x[rho[e]] = cmul(x[rho[e]], run);
  }
}

template <int SGN>
__device__ __forceinline__ void xlane_dif(float2* x, int lane) {
#pragma unroll
  for (int h = 32; h >= 1; h >>= 1) {
    const int e = (lane & (h - 1)) * (32 / h);
    float s, c;
    __sincosf((float)e * 0.09817477042f, &s, &c);  // 2pi/64
    float2 w = make_float2(c, SGN > 0 ? s : -s);
    const bool hi = (lane & h) != 0;
#pragma unroll
    for (int r = 0; r < 16; ++r) {
      float2 t = x[r];
      float2 p;
      p.x = __shfl_xor(t.x, h, 64);
      p.y = __shfl_xor(t.y, h, 64);
      x[r] = hi ? cmul(csub(p, t), w) : cadd(t, p);
    }
  }
}

template <int SGN>
__device__ __forceinline__ void wfft1024_dif(float2* x, int lane) {
  dft16_dif<SGN>(x);
  midtw<SGN>(x, lane);
  xlane_dif<SGN>(x, lane);
}

// -------- paired (two-row) variants: shared twiddles, 2x ILP per stage ----
template <int SGN>
__device__ __forceinline__ void midtw2(float2* x, float2* y, int lane) {
  const int rho[16] = {0, 8, 4, 12, 2, 10, 6, 14, 1, 9, 5, 13, 3, 11, 7, 15};
  float s, c;
  __sincosf((float)lane * 0.00613592315f, &s, &c);
  float2 w = make_float2(c, SGN > 0 ? s : -s);
  float2 run = w;
  x[8] = cmul(x[8], run);
  y[8] = cmul(y[8], run);
#pragma unroll
  for (int e = 2; e < 16; ++e) {
    run = cmul(run, w);
    x[rho[e]] = cmul(x[rho[e]], run);
    y[rho[e]] = cmul(y[rho[e]], run);
  }
}

__device__ __forceinline__ void midtw_inv2(float2* x, float2* y, int lane) {
  const int rho[16] = {0, 8, 4, 12, 2, 10, 6, 14, 1, 9, 5, 13, 3, 11, 7, 15};
  float s, c;
  __sincosf((float)lane * 0.00613592315f, &s, &c);
  float2 w = make_float2(c, -s);
  float2 run = w;
  x[8] = cmulc(x[8], run);
  y[8] = cmulc(y[8], run);
#pragma unroll
  for (int e = 2; e < 16; ++e) {
    run = cmul(run, w);
    x[rho[e]] = cmulc(x[rho[e]], run);
    y[rho[e]] = cmulc(y[rho[e]], run);
  }
}

template <int SGN>
__device__ __forceinline__ void xlane_dif2(float2* x, float2* y, int lane) {
#pragma unroll
  for (int h = 32; h >= 1; h >>= 1) {
    const int e = (lane & (h - 1)) * (32 / h);
    float s, c;
    __sincosf((float)e * 0.09817477042f, &s, &c);
    float2 w = make_float2(c, SGN > 0 ? s : -s);
    const bool hi = (lane & h) != 0;
#pragma unroll
    for (int r = 0; r < 16; ++r) {
      float2 t = x[r];
      float2 p;
      p.x = __shfl_xor(t.x, h, 64);
      p.y = __shfl_xor(t.y, h, 64);
      x[r] = hi ? cmul(csub(p, t), w) : cadd(t, p);
    }
#pragma unroll
    for (int r = 0; r < 16; ++r) {
      float2 t = y[r];
      float2 p;
      p.x = __shfl_xor(t.x, h, 64);
      p.y = __shfl_xor(t.y, h, 64);
      y[r] = hi ? cmul(csub(p, t), w) : cadd(t, p);
    }
  }
}

__device__ __forceinline__ void xlane_dit_inv2(float2* x, float2* y, int lane) {
#pragma unroll
  for (int h = 1; h <= 32; h <<= 1) {
    const int e = (lane & (h - 1)) * (32 / h);
    float s, c;
    __sincosf((float)e * 0.09817477042f, &s, &c);
    float2 w = make_float2(c, -s);
    const bool hi = (lane & h) != 0;
#pragma unroll
    for (int r = 0; r < 16; ++r) {
      float2 t = x[r];
      if (hi) t = cmulc(t, w);
      float2 p;
      p.x = __shfl_xor(t.x, h, 64);
      p.y = __shfl_xor(t.y, h, 64);
      x[r] = hi ? csub(p, t) : cadd(t, p);
    }
#pragma unroll
    for (int r = 0; r < 16; ++r) {
      float2 t = y[r];
      if (hi) t = cmulc(t, w);
      float2 p;
      p.x = __shfl_xor(t.x, h, 64);
      p.y = __shfl_xor(t.y, h, 64);
      y[r] = hi ? csub(p, t) : cadd(t, p);
    }
  }
}

template <int SGN>
__device__ __forceinline__ void wfft1024_dif2(float2* x, float2* y, int lane) {
  dft16_dif<SGN>(x);
  dft16_dif<SGN>(y);
  midtw2<SGN>(x, y, lane);
  xlane_dif2<SGN>(x, y, lane);
}
__device__ __forceinline__ void wfft1024_inv2(float2* x, float2* y, int lane) {
  xlane_dit_inv2(x, y, lane);
  midtw_inv2(x, y, lane);
  dit16_inv(x);
  dit16_inv(y);
}

// spectral gain; 1/N^2 folded in. alpha==1: cos(atan t) == rsqrt(1+t^2).
__device__ __forceinline__ float gainw(float re, float im, float alpha, bool a1) {
  float mag2 = re * re + im * im;
  float t = 0.5f * __logf(mag2 + 1e-20f);
  if (a1) return __builtin_amdgcn_rsqf(fmaf(t, t, 1.0f)) * (1.0f / 1048576.0f);
  return __cosf(alpha * atanf(t)) * (1.0f / 1048576.0f);
}

// ------------------------------------------------- k0: dtype detect + alpha
__global__ void k0_detect(const unsigned* __restrict__ q,
                          const void* __restrict__ alphap, int* __restrict__ flags) {
  __shared__ float smax[256];
  __shared__ int szero[256];
  int t = threadIdx.x;
  float mx = 0.f; int zc = 0;
  for (int i = t; i < 16384; i += 256) {
    unsigned w = q[i];
    unsigned lo = w & 0xFFFFu;
    float v = fabsf(__uint_as_float(lo << 16));
    if (!(v <= 1e30f)) v = 1e30f;
    mx = fmaxf(mx, v);
    zc += (lo == 0u);
  }
  smax[t] = mx; szero[t] = zc;
  __syncthreads();
  for (int s = 128; s > 0; s >>= 1) {
    if (t < s) { smax[t] = fmaxf(smax[t], smax[t + s]); szero[t] += szero[t + s]; }
    __syncthreads();
  }
  if (t == 0) {
    int isf32 = (smax[0] > 100.f) || (szero[0] > 12288);
    flags[0] = isf32;
    float alpha = isf32 ? *(const float*)alphap : bf2f(*(const short*)alphap);
    ((float*)flags)[1] = alpha;
  }
}

// ------------------------------------------------- k1: QKV projection (XCD-swizzled)
// BK=64. Outputs transposed: O[plane][d][s].
__global__ __launch_bounds__(256) void k1_qkv(
    const void* __restrict__ x,
    const void* __restrict__ Wq, const void* __restrict__ bq,
    const void* __restrict__ Wk, const void* __restrict__ bk,
    const void* __restrict__ Wv, const void* __restrict__ bv,
    short* __restrict__ Qt, short* __restrict__ Kt, short* __restrict__ Vt,
    const int* __restrict__ flags)
{
  __shared__ __align__(16) char smem[128 * PITCH1 * 2 * 2];  // 36864 B
  short* As = (short*)smem;
  short* Bs = As + 128 * PITCH1;
  short* Ct = (short*)smem;  // epilogue overlay (34816 B)
  const int isf32 = flags[0];
  const int t = threadIdx.x;
  const int lb = blockIdx.x;
  const int m0 = ((lb & 7) * 4 + ((lb >> 3) & 3)) * 128;
  const int n0 = (lb >> 5) * 128;
  const int which = blockIdx.y;
  const void* __restrict__ W = (which == 0) ? Wq : (which == 1) ? Wk : Wv;
  const void* __restrict__ bias = (which == 0) ? bq : (which == 1) ? bk : bv;
  const int lane = t & 63, wvi = t >> 6;
  const int wr = wvi >> 1, wc = wvi & 1;
  const int lm = lane & 15, lq = lane >> 4;
  f32x4 acc[4][4] = {};

  for (int k0 = 0; k0 < 1024; k0 += 64) {
    __syncthreads();
#pragma unroll
    for (int i = 0; i < 4; ++i) {
      int l = t + i * 256;
      int row = l >> 3, kk = (l & 7) << 3;
      *(short8*)&As[row * PITCH1 + kk] = ld8(x, (size_t)(m0 + row) * 1024 + k0 + kk, isf32);
      *(short8*)&Bs[row * PITCH1 + kk] = ld8(W, (size_t)(n0 + row) * 1024 + k0 + kk, isf32);
    }
    __syncthreads();
#pragma unroll
    for (int kh = 0; kh < 2; ++kh) {
      short8 af[4], bf[4];
#pragma unroll
      for (int a = 0; a < 4; ++a)
        af[a] = *(const short8*)&As[(wr * 64 + a * 16 + lm) * PITCH1 + kh * 32 + lq * 8];
#pragma unroll
      for (int b = 0; b < 4; ++b)
        bf[b] = *(const short8*)&Bs[(wc * 64 + b * 16 + lm) * PITCH1 + kh * 32 + lq * 8];
#pragma unroll
      for (int a = 0; a < 4; ++a)
#pragma unroll
        for (int b = 0; b < 4; ++b)
          acc[a][b] = __builtin_amdgcn_mfma_f32_16x16x32_bf16(af[a], bf[b], acc[a][b], 0, 0, 0);
    }
  }

  __syncthreads();
#pragma unroll
  for (int a = 0; a < 4; ++a)
#pragma unroll
    for (int b = 0; b < 4; ++b) {
      int col = wc * 64 + b * 16 + lm;
      float bv_ = ldf(bias, n0 + col, isf32);
#pragma unroll
      for (int r = 0; r < 4; ++r) {
        int row = wr * 64 + a * 16 + lq * 4 + r;
        Ct[row * 136 + col] = f2bf(acc[a][b][r] + bv_);
      }
    }
  __syncthreads();

  short* __restrict__ O = (which == 0) ? Qt : (which == 1) ? Kt : Vt;
#pragma unroll
  for (int j = 0; j < 8; ++j) {
    int id = t + j * 256;
    int d128 = id & 127, sg = (id >> 7) * 8;
    short vals[8];
#pragma unroll
    for (int i = 0; i < 8; ++i) vals[i] = Ct[(sg + i) * 136 + d128];
    int col = n0 + d128;
    int h = col >> 6, d = col & 63;
    int bb = m0 >> 10, sbase = (m0 & 1023) + sg;
    *(short8*)&O[(((size_t)(bb * 16 + h)) << 16) + ((size_t)d << 10) + sbase] = *(short8*)vals;
  }
}

// ------------------------------------------------- kA: column FFTs of Q and K
// ONE dispatch, all 64 planes: grid (32, 64), 128 threads (2 waves).
__global__ __launch_bounds__(128) void kA_qkfft(
    const short* __restrict__ Qt, const short* __restrict__ Kt,
    __half2* __restrict__ Qhat, __half2* __restrict__ Khat)
{
  __shared__ float2 sbuf[2][1024];
  const int lane = threadIdx.x & 63, w = threadIdx.x >> 6;
  const int z = blockIdx.y;
  const int bx = blockIdx.x;
  if (bx < 16) {
    const short* qp = Qt + ((size_t)z << 16);
    const int d0 = bx * 4 + w * 2;
    float2 x[16], y[16];
#pragma unroll
    for (int j = 0; j < 16; ++j) {
      x[j] = make_float2(0.125f * bf2f(qp[(d0 << 10) + lane + 64 * j]), 0.f);
      y[j] = make_float2(0.125f * bf2f(qp[((d0 + 1) << 10) + lane + 64 * j]), 0.f);
    }
    wfft1024_dif2<-1>(x, y, lane);
    __half2* o0 = Qhat + (((size_t)(z * 64 + d0)) << 10);
    __half2* o1 = o0 + 1024;
#pragma unroll
    for (int r = 0; r < 16; ++r) {
      o0[lane + 64 * r] = __float22half2_rn(x[r]);
      o1[lane + 64 * r] = __float22half2_rn(y[r]);
    }
  } else {
    const short* kp = Kt + ((size_t)z << 16);
    const int p = (bx - 16) * 2 + w;
    const int d0 = 2 * p;
    float2 x[16];
#pragma unroll
    for (int j = 0; j < 16; ++j)
      x[j] = make_float2(bf2f(kp[(d0 << 10) + lane + 64 * j]),
                         bf2f(kp[((d0 + 1) << 10) + lane + 64 * j]));
    wfft1024_dif<-1>(x, lane);
    const int rho[16] = {0, 8, 4, 12, 2, 10, 6, 14, 1, 9, 5, 13, 3, 11, 7, 15};
    const int bl6 = ((lane & 1) << 5) | ((lane & 2) << 3) | ((lane & 4) << 1) |
                    ((lane & 8) >> 1) | ((lane & 16) >> 3) | ((lane & 32) >> 5);
    float2* buf = sbuf[w];
#pragma unroll
    for (int r = 0; r < 16; ++r) buf[rho[r] + 16 * bl6] = x[r];
    __half2* o0 = Khat + (size_t)(z * 64 + d0) * 520;
    __half2* o1 = o0 + 520;
#pragma unroll 1
    for (int jj = 0; jj < 9; ++jj) {
      int v = lane + 64 * jj;
      if (v <= 512) {
        float2 A = buf[v], B = buf[(1024 - v) & 1023];
        // K1 = (Z + conj(Z~))/2 ; K2 = (Z - conj(Z~))/(2i)
        o0[v] = __float22half2_rn(make_float2((A.x + B.x) * 0.5f, (A.y - B.y) * 0.5f));
        o1[v] = __float22half2_rn(make_float2((A.y + B.y) * 0.5f, (B.x - A.x) * 0.5f));
      }
    }
  }
}

// ------------------------------------------------- kB: F2D = Khat x Qhat^T + gain
// C[v][u-slot], M=64 (v), N=128 (u), K=64 (d). fp16 MFMA, f32 accum.
__global__ __launch_bounds__(256) void kB_specmm(
    const __half2* __restrict__ Qhat, const __half2* __restrict__ Khat,
    __half2* __restrict__ Ct, const int* __restrict__ flags, int bh0)
{
  __shared__ unsigned short Are[64][72], Aim[64][72], Bre[128][72], Bim[128][72];
  const int t = threadIdx.x;
  const int u0 = blockIdx.x * 128;
  const int v0 = blockIdx.y * 64;
  const int zl = blockIdx.z;
  const int z = bh0 + zl;
  const float alpha = ((const float*)flags)[1];
  const bool a1 = (alpha == 1.0f);
  {
    const int d = t >> 2;
    const ushort2* src = (const ushort2*)(Khat + (size_t)(z * 64 + d) * 520);
    int vb = (t & 3) * 16;
#pragma unroll
    for (int j = 0; j < 16; ++j) {
      int v = v0 + vb + j;
      if (v > 519) v = 519;
      ushort2 e = src[v];
      int row = vb + j;
      int dc = d ^ (((row >> 4) & 3) << 4);  // bank-spread swizzle
      Are[row][dc] = e.x;
      Aim[row][dc] = e.y;
    }
    const ushort2* srcb = (const ushort2*)(Qhat + (((size_t)(z * 64 + d)) << 10) + u0);
    int ub = (t & 3) * 32;
#pragma unroll
    for (int j = 0; j < 32; ++j) {
      ushort2 e = srcb[ub + j];
      int row = ub + j;
      int dc = d ^ (((row >> 5) & 3) << 4);
      Bre[row][dc] = e.x;
      Bim[row][dc] = e.y;
    }
  }
  __syncthreads();

  const int lane = t & 63, wc = t >> 6;
  const int lm = lane & 15, lq = lane >> 4;
  f32x4 cre[4][2] = {}, cim[4][2] = {};
#pragma unroll
  for (int ks = 0; ks < 2; ++ks) {
    half8 ar[4], ai[4], aiN[4], br[2], bi[2];
#pragma unroll
    for (int a = 0; a < 4; ++a) {
      int dc = (ks * 32 + lq * 8) ^ ((a & 3) << 4);
      ar[a] = *(const half8*)&Are[a * 16 + lm][dc];
      ai[a] = *(const half8*)&Aim[a * 16 + lm][dc];
      int4 tm = *(int4*)&ai[a];
      tm.x ^= 0x80008000; tm.y ^= 0x80008000; tm.z ^= 0x80008000; tm.w ^= 0x80008000;
      aiN[a] = *(half8*)&tm;
    }
#pragma unroll
    for (int n = 0; n < 2; ++n) {
      int dc = (ks * 32 + lq * 8) ^ ((wc & 3) << 4);
      br[n] = *(const half8*)&Bre[wc * 32 + n * 16 + lm][dc];
      bi[n] = *(const half8*)&Bim[wc * 32 + n * 16 + lm][dc];
    }
#pragma unroll
    for (int a = 0; a < 4; ++a)
#pragma unroll
      for (int n = 0; n < 2; ++n) {
        cre[a][n] = __builtin_amdgcn_mfma_f32_16x16x32_f16(ar[a], br[n], cre[a][n], 0, 0, 0);
        cre[a][n] = __builtin_amdgcn_mfma_f32_16x16x32_f16(aiN[a], bi[n], cre[a][n], 0, 0, 0);
        cim[a][n] = __builtin_amdgcn_mfma_f32_16x16x32_f16(ar[a], bi[n], cim[a][n], 0, 0, 0);
        cim[a][n] = __builtin_amdgcn_mfma_f32_16x16x32_f16(ai[a], br[n], cim[a][n], 0, 0, 0);
      }
  }

  __half2* outp = Ct + (size_t)zl * 513 * 1024 + u0 + wc * 32;
#pragma unroll
  for (int a = 0; a < 4; ++a)
#pragma unroll
    for (int r = 0; r < 4; ++r) {
      int v = v0 + a * 16 + lq * 4 + r;
      if (v < 513) {
#pragma unroll
        for (int n = 0; n < 2; ++n) {
          float re = cre[a][n][r], im = cim[a][n][r];
          float wf = gainw(re, im, alpha, a1);
          outp[(size_t)v * 1024 + n * 16 + lm] =
              __float22half2_rn(make_float2(re * wf, im * wf));
        }
      }
    }
}

// ------------------------------------------------- k4: inverse u-FFT (in place)
// Reads F~[v][u-slot] (scrambled-u), writes G[v][q] natural. Two rows/wave.
__global__ __launch_bounds__(256) void k4_invfft(__half2* __restrict__ Ct)
{
  const int lane = threadIdx.x & 63;
  const int w = threadIdx.x >> 6;
  const int gv0 = blockIdx.x * 8 + w * 2;
  if (gv0 > 512) return;
  const bool has1 = (gv0 + 1 <= 512);
  __half2* __restrict__ row0 = Ct + (size_t)blockIdx.y * 513 * 1024 + ((size_t)gv0 << 10);
  __half2* __restrict__ row1 = row0 + 1024;
  float2 x[16], y[16];
#pragma unroll
  for (int j = 0; j < 16; ++j) x[j] = __half22float2(row0[lane + 64 * j]);
  if (has1) {
#pragma unroll
    for (int j = 0; j < 16; ++j) y[j] = __half22float2(row1[lane + 64 * j]);
  } else {
#pragma unroll
    for (int j = 0; j < 16; ++j) y[j] = make_float2(0.f, 0.f);
  }
  wfft1024_inv2(x, y, lane);
#pragma unroll
  for (int j = 0; j < 16; ++j) row0[lane + 64 * j] = __float22half2_rn(x[j]);
  if (has1) {
#pragma unroll
    for (int j = 0; j < 16; ++j) row1[lane + 64 * j] = __float22half2_rn(y[j]);
  }
}

// ------------------------------------------------- k56: inverse row FFT + softmax + PV
// 512 threads / 8 waves, single round: wave w owns p-pair w (rows 2w, 2w+1).
// Gbuf pitch 2064 B (516 words = 4 mod 32 -> staging writes uniform 2-way).
// P scatter via rho-involution in-register reorder -> 2x ds_write_b128/row.
__global__ __launch_bounds__(512) void k56_softmax_av(
    const __half2* __restrict__ Ct, const short* __restrict__ Vt,
    short* __restrict__ ctx, int bh0)
{
  __shared__ __align__(16) char GP[33280];
  const int tid = threadIdx.x;
  const int q0 = blockIdx.x * 16, z = blockIdx.y;
  const int lane = tid & 63, w = tid >> 6;  // w = 0..7
  const int lm = lane & 15, lq = lane >> 4;
  const __half2* __restrict__ in = Ct + (size_t)z * 513 * 1024;
#define GROW(m) ((__half2*)(GP + (m) * 2064))
  for (int id = tid; id < 2052; id += 512) {
    int v = id >> 2, qq = (id & 3) * 4;
    int4 o = *(const int4*)&in[(size_t)v * 1024 + q0 + qq];
    __half2* op = (__half2*)&o;
#pragma unroll
    for (int i = 0; i < 4; ++i) GROW(qq + i)[v] = op[i];
  }
  short* P = (short*)GP;  // row m at m*1040 shorts
  const int bl6 = ((lane & 1) << 5) | ((lane & 2) << 3) | ((lane & 4) << 1) |
                  ((lane & 8) >> 1) | ((lane & 16) >> 3) | ((lane & 32) >> 5);
  __syncthreads();  // Gbuf ready

  const int p = w;
  const __half2* g1 = GROW(2 * p);
  const __half2* g2 = GROW(2 * p + 1);
  float2 x[16];
#pragma unroll
  for (int j = 0; j < 16; ++j) {
    int v = lane + 64 * j;
    float2 a, b;
    if (v <= 512) {
      a = __half22float2(g1[v]);
      b = __half22float2(g2[v]);
    } else {
      int v2 = 1024 - v;
      float2 aa = __half22float2(g1[v2]), bb = __half22float2(g2[v2]);
      a = make_float2(aa.x, -aa.y);
      b = make_float2(bb.x, -bb.y);
    }
    x[j] = make_float2(a.x - b.y, a.y + b.x);
  }

  wfft1024_dif<1>(x, lane);  // sum_v z W^{+vk}: Re = row 2p, Im = row 2p+1

  float m1 = -3.4e38f, m2 = -3.4e38f;
#pragma unroll
  for (int j = 0; j < 16; ++j) { m1 = fmaxf(m1, x[j].x); m2 = fmaxf(m2, x[j].y); }
#pragma unroll
  for (int s = 32; s > 0; s >>= 1) {
    m1 = fmaxf(m1, __shfl_xor(m1, s, 64));
    m2 = fmaxf(m2, __shfl_xor(m2, s, 64));
  }
  float s1 = 0.f, s2 = 0.f;
#pragma unroll
  for (int j = 0; j < 16; ++j) {
    float e1 = __expf(x[j].x - m1), e2 = __expf(x[j].y - m2);
    x[j] = make_float2(e1, e2);
    s1 += e1; s2 += e2;
  }
#pragma unroll
  for (int s = 32; s > 0; s >>= 1) {
    s1 += __shfl_xor(s1, s, 64);
    s2 += __shfl_xor(s2, s, 64);
  }
  float inv1 = 1.0f / s1, inv2 = 1.0f / s2;

  __syncthreads();  // ALL G reads done before ANY P writes

  {
    // rho is an involution: position pos in the 16-block at 16*bl6 holds
    // x[rho[pos]]. Build pos-ordered short8 pairs -> 2x b128 per row.
    const int rho[16] = {0, 8, 4, 12, 2, 10, 6, 14, 1, 9, 5, 13, 3, 11, 7, 15};
    short a0[16], a1[16];
#pragma unroll
    for (int pos = 0; pos < 16; ++pos) {
      const int j = rho[pos];
      a0[pos] = f2bf(x[j].x * inv1);
      a1[pos] = f2bf(x[j].y * inv2);
    }
    short* dst0 = &P[(2 * p) * 1040 + 16 * bl6];
    short* dst1 = &P[(2 * p + 1) * 1040 + 16 * bl6];
    *(short8*)dst0       = *(short8*)&a0[0];
    *(short8*)(dst0 + 8) = *(short8*)&a0[8];
    *(short8*)dst1       = *(short8*)&a1[0];
    *(short8*)(dst1 + 8) = *(short8*)&a1[8];
  }
  __syncthreads();  // P complete

  // PV: wave w covers k in [w*128, w*128+128)
  const short* __restrict__ Vp = Vt + ((size_t)(bh0 + z) << 16);
  f32x4 acc[4] = {};
#pragma unroll
  for (int ks = 0; ks < 4; ++ks) {
    int k0 = w * 128 + ks * 32;
    short8 a0 = *(const short8*)&P[lm * 1040 + k0 + lq * 8];
#pragma unroll
    for (int b = 0; b < 4; ++b) {
      short8 bv = *(const short8*)&Vp[(size_t)(b * 16 + lm) * 1024 + k0 + lq * 8];
      acc[b] = __builtin_amdgcn_mfma_f32_16x16x32_bf16(a0, bv, acc[b], 0, 0, 0);
    }
  }
  __syncthreads();  // all P reads done; reuse GP for reduction
  float* red = (float*)GP;  // [w=8][q=16][d=64] = 32 KB
#pragma unroll
  for (int b = 0; b < 4; ++b)
#pragma unroll
    for (int r = 0; r < 4; ++r)
      red[(w * 16 + lq * 4 + r) * 64 + b * 16 + lm] = acc[b][r];
  __syncthreads();
  if (tid < 256) {
    int q = tid >> 4, d0 = (tid & 15) * 4;
    float s0 = 0.f, s1_ = 0.f, s2_ = 0.f, s3 = 0.f;
#pragma unroll
    for (int ww = 0; ww < 8; ++ww) {
      const float* rr = &red[(ww * 16 + q) * 64 + d0];
      s0 += rr[0]; s1_ += rr[1]; s2_ += rr[2]; s3 += rr[3];
    }
    short o4[4] = {f2bf(s0), f2bf(s1_), f2bf(s2_), f2bf(s3)};
    *(int2*)&ctx[(((size_t)(bh0 + z)) << 16) + (size_t)(q0 + q) * 64 + d0] = *(int2*)o4;
  }
#undef GROW
}

// ------------------------------------------------- k7: out = ctx @ Wo^T + bo (XCD-swizzled)
__global__ __launch_bounds__(256) void k7_out(
    const short* __restrict__ ctx, const void* __restrict__ Wo,
    const void* __restrict__ bo, void* __restrict__ out,
    const int* __restrict__ flags)
{
  __shared__ __align__(16) char smem[128 * 136 * 2];
  short* As = (short*)smem;
  short* Bs = As + 128 * PITCH;
  short* Ct = (short*)smem;
  const int isf32 = flags[0];
  const int t = threadIdx.x;
  const int lb = blockIdx.x;
  const int m0 = ((lb & 7) * 4 + ((lb >> 3) & 3)) * 128;
  const int n0 = (lb >> 5) * 128;
  const int lane = t & 63, wvi = t >> 6;
  const int wr = wvi >> 1, wc = wvi & 1;
  const int lm = lane & 15, lq = lane >> 4;
  f32x4 acc[4][4] = {};

  for (int k0 = 0; k0 < 1024; k0 += 32) {
    __syncthreads();
#pragma unroll
    for (int i = 0; i < 2; ++i) {
      int l = t + i * 256;
      int row = l >> 2, kk = (l & 3) << 3;
      int n = m0 + row, e = k0 + kk;
      size_t aaddr = (((size_t)((n >> 10) * 16 + (e >> 6))) << 16) + (size_t)((n & 1023) << 6) + (e & 63);
      *(int4*)&As[row * PITCH + kk] = *(const int4*)&ctx[aaddr];
      *(short8*)&Bs[row * PITCH + kk] = ld8(Wo, (size_t)(n0 + row) * 1024 + e, isf32);
    }
    __syncthreads();
    short8 af[4], bf[4];
#pragma unroll
    for (int a = 0; a < 4; ++a) af[a] = *(const short8*)&As[(wr * 64 + a * 16 + lm) * PITCH + lq * 8];
#pragma unroll
    for (int b = 0; b < 4; ++b) bf[b] = *(const short8*)&Bs[(wc * 64 + b * 16 + lm) * PITCH + lq * 8];
#pragma unroll
    for (int a = 0; a < 4; ++a)
#pragma unroll
      for (int b = 0; b < 4; ++b)
        acc[a][b] = __builtin_amdgcn_mfma_f32_16x16x32_bf16(af[a], bf[b], acc[a][b], 0, 0, 0);
  }

  if (isf32) {
#pragma unroll
    for (int a = 0; a < 4; ++a)
#pragma unroll
      for (int b = 0; b < 4; ++b) {
        int col = n0 + wc * 64 + b * 16 + lm;
        float bo_ = ldf(bo, col, 1);
#pragma unroll
        for (int r = 0; r < 4; ++r) {
          int row = m0 + wr * 64 + a * 16 + lq * 4 + r;
          ((float*)out)[(size_t)row * 1024 + col] = acc[a][b][r] + bo_;
        }
      }
    return;
  }
  __syncthreads();
#pragma unroll
  for (int a = 0; a < 4; ++a)
#pragma unroll
    for (int b = 0; b < 4; ++b) {
      int col = wc * 64 + b * 16 + lm;
      float bo_ = ldf(bo, n0 + col, 0);
#pragma unroll
      for (int r = 0; r < 4; ++r) {
        int row = wr * 64 + a * 16 + lq * 4 + r;
        Ct[row * 136 + col] = f2bf(acc[a][b][r] + bo_);
      }
    }
  __syncthreads();
#pragma unroll
  for (int j = 0; j < 8; ++j) {
    int id = t + j * 256;
    int row = id >> 4, c16 = (id & 15) * 8;
    short8 v = *(const short8*)&Ct[row * 136 + c16];
    *(short8*)&((short*)out)[(size_t)(m0 + row) * 1024 + n0 + c16] = v;
  }
}

// ------------------------------------------------- launch
extern "C" void kernel_launch(void* const* d_in, const int* in_sizes, int n_in,
                              void* d_out, int out_size, void* d_ws, size_t ws_size,
                              hipStream_t stream)
{
  const void* x  = d_in[0];
  const void* Wq = d_in[1];
  const void* bq = d_in[2];
  const void* Wk = d_in[3];
  const void* bk = d_in[4];
  const void* Wv = d_in[5];
  const void* bv = d_in[6];
  const void* Wo = d_in[7];
  const void* bo = d_in[8];
  const void* alphap = d_in[9];
  char* ws = (char*)d_ws;

  const size_t PLANE_CT = (size_t)513 * 1024 * 4;  // 2,101,248 B
  const size_t QH_SZ = (size_t)64 * 64 * 1024 * 4; // 16 MiB
  const size_t KH_SZ = (size_t)64 * 64 * 520 * 4;  // 8.125 MiB

  // ---- big path layout: Ct-all overlays Qt/Kt ----
  const size_t B_CT  = 0;
  const size_t B_VT  = 64 * PLANE_CT;            // 134,479,872
  const size_t B_CX  = B_VT + ((size_t)8u << 20);
  const size_t B_QH  = B_CX + ((size_t)8u << 20);
  const size_t B_KH  = B_QH + QH_SZ;
  const size_t B_FL  = B_KH + KH_SZ;
  const size_t B_NEED = B_FL + 256;

  if (ws_size >= B_NEED) {
    short*   Qt   = (short*)(ws);
    short*   Kt   = (short*)(ws + ((size_t)8u << 20));
    short*   Vt   = (short*)(ws + B_VT);
    short*   ctx  = (short*)(ws + B_CX);
    __half2* Ct   = (__half2*)(ws + B_CT);   // overlays Qt/Kt (dead after kA)
    __half2* Qhat = (__half2*)(ws + B_QH);
    __half2* Khat = (__half2*)(ws + B_KH);
    int*     flags = (int*)(ws + B_FL);

    k0_detect<<<1, 256, 0, stream>>>((const unsigned*)x, alphap, flags);
    k1_qkv<<<dim3(256, 3), 256, 0, stream>>>(x, Wq, bq, Wk, bk, Wv, bv, Qt, Kt, Vt, flags);
    kA_qkfft<<<dim3(32, 64), 128, 0, stream>>>(Qt, Kt, Qhat, Khat);
    kB_specmm<<<dim3(8, 9, 64), 256, 0, stream>>>(Qhat, Khat, Ct, flags, 0);
    k4_invfft<<<dim3(65, 64), 256, 0, stream>>>(Ct);
    k56_softmax_av<<<dim3(64, 64), 512, 0, stream>>>(Ct, Vt, ctx, 0);
    k7_out<<<256, 256, 0, stream>>>(ctx, Wo, bo, d_out, flags);
    return;
  }

  // ---- chunked fallback (proven ~59.9 MiB layout) ----
  const size_t VT_OFF = (size_t)17u << 20;
  const size_t CX_OFF = (size_t)25u << 20;
  const size_t QH_OFF = (size_t)33u << 20;
  const size_t KH_OFF = QH_OFF + QH_SZ;
  const size_t FL_OFF = KH_OFF + KH_SZ;

  short*   Qt   = (short*)(ws);
  short*   Kt   = (short*)(ws + ((size_t)8u << 20));
  short*   Vt   = (short*)(ws + VT_OFF);
  short*   ctx  = (short*)(ws + CX_OFF);
  __half2* Ct   = (__half2*)(ws);          // overlays Qt/Kt (dead after kA)
  __half2* Qhat = (__half2*)(ws + QH_OFF);
  __half2* Khat = (__half2*)(ws + KH_OFF);
  int*     flags = (int*)(ws + FL_OFF);

  k0_detect<<<1, 256, 0, stream>>>((const unsigned*)x, alphap, flags);
  k1_qkv<<<dim3(256, 3), 256, 0, stream>>>(x, Wq, bq, Wk, bk, Wv, bv, Qt, Kt, Vt, flags);
  kA_qkfft<<<dim3(32, 64), 128, 0, stream>>>(Qt, Kt, Qhat, Khat);
  for (int c = 0; c < 8; ++c) {
    int bh0 = c * 8;
    kB_specmm<<<dim3(8, 9, 8), 256, 0, stream>>>(Qhat, Khat, Ct, flags, bh0);
    k4_invfft<<<dim3(65, 8), 256, 0, stream>>>(Ct);
    k56_softmax_av<<<dim3(64, 8), 512, 0, stream>>>(Ct, Vt, ctx, bh0);
  }
  k7_out<<<256, 256, 0, stream>>>(ctx, Wo, bo, d_out, flags);
}